// Round 11
// baseline (1032.696 us; speedup 1.0000x reference)
//
#include <hip/hip_runtime.h>
#include <hip/hip_bf16.h>
#include <cstdint>

#define BIGF 1e30f
constexpr int LB   = 4096;           // L = H*W
constexpr int NB   = 8;              // batch
constexpr int MROWS = NB * LB;       // 32768 pixel rows
constexpr int LSP  = 4104;           // level-start stride per batch

// ---------------- helpers ----------------
__device__ __forceinline__ float warp_sum(float v) {
#pragma unroll
  for (int off = 32; off; off >>= 1) v += __shfl_xor(v, off);
  return v;
}

__device__ __forceinline__ float block_sum256(float v) {
  __shared__ float sm[4];
  v = warp_sum(v);
  __syncthreads();
  if ((threadIdx.x & 63) == 0) sm[threadIdx.x >> 6] = v;
  __syncthreads();
  return sm[0] + sm[1] + sm[2] + sm[3];
}

// ---------------- LayerNorm over last dim 128 ----------------
__global__ __launch_bounds__(256) void ln128_kernel(
    const float* __restrict__ X, const float* __restrict__ g,
    const float* __restrict__ bb, float* __restrict__ O, float eps) {
  int wave = threadIdx.x >> 6, lane = threadIdx.x & 63;
  int row = blockIdx.x * 4 + wave;
  const float* xr = X + (size_t)row * 128;
  float x0 = xr[lane], x1 = xr[lane + 64];
  float mu = warp_sum(x0 + x1) * (1.0f / 128.0f);
  float d0 = x0 - mu, d1 = x1 - mu;
  float var = warp_sum(d0 * d0 + d1 * d1) * (1.0f / 128.0f);
  float s = 1.0f / sqrtf(var + eps);
  float* orow = O + (size_t)row * 128;
  orow[lane]      = d0 * s * g[lane]      + bb[lane];
  orow[lane + 64] = d1 * s * g[lane + 64] + bb[lane + 64];
}

// ---------------- f32 GEMM: C = A[M,K] @ W[N,K]^T, 128x128 tile, 8x8 acc ----------------
// EPI 1: split+silu (N=512): n<256 -> C[m*256+n], n>=256 -> C2[m*256+n-256]=silu
// EPI 2: C = acc + addsrc
// EPI 3: C = gelu(acc + bias)
// EPI 4: C = acc + bias + addsrc
template<int EPI>
__global__ __launch_bounds__(256) void gemm_kernel(
    const float* __restrict__ A, const float* __restrict__ W,
    float* __restrict__ C, float* __restrict__ C2,
    const float* __restrict__ bias, const float* __restrict__ addsrc,
    int M, int N, int K) {
  __shared__ float As[32][132];
  __shared__ float Bs[32][132];
  int t = threadIdx.x;
  int tx = t & 15, ty = t >> 4;          // 16 x 16 threads
  int bm = blockIdx.y * 128, bn = blockIdx.x * 128;
  float acc[8][8] = {};
  for (int k0 = 0; k0 < K; k0 += 32) {
#pragma unroll
    for (int hh = 0; hh < 4; ++hh) {
      int q = t + hh * 256;              // 0..1023
      int r = q >> 3, kc = q & 7;
      float4 a4 = *reinterpret_cast<const float4*>(A + (size_t)(bm + r) * K + k0 + kc * 4);
      float4 b4 = *reinterpret_cast<const float4*>(W + (size_t)(bn + r) * K + k0 + kc * 4);
      As[kc * 4 + 0][r] = a4.x; As[kc * 4 + 1][r] = a4.y;
      As[kc * 4 + 2][r] = a4.z; As[kc * 4 + 3][r] = a4.w;
      Bs[kc * 4 + 0][r] = b4.x; Bs[kc * 4 + 1][r] = b4.y;
      Bs[kc * 4 + 2][r] = b4.z; Bs[kc * 4 + 3][r] = b4.w;
    }
    __syncthreads();
#pragma unroll
    for (int kk = 0; kk < 32; ++kk) {
      float4 a0 = *reinterpret_cast<const float4*>(&As[kk][ty * 4]);
      float4 a1 = *reinterpret_cast<const float4*>(&As[kk][64 + ty * 4]);
      float4 b0 = *reinterpret_cast<const float4*>(&Bs[kk][tx * 4]);
      float4 b1 = *reinterpret_cast<const float4*>(&Bs[kk][64 + tx * 4]);
      float aa[8] = {a0.x, a0.y, a0.z, a0.w, a1.x, a1.y, a1.z, a1.w};
      float bb2[8] = {b0.x, b0.y, b0.z, b0.w, b1.x, b1.y, b1.z, b1.w};
#pragma unroll
      for (int i = 0; i < 8; ++i)
#pragma unroll
        for (int j = 0; j < 8; ++j) acc[i][j] += aa[i] * bb2[j];
    }
    __syncthreads();
  }
#pragma unroll
  for (int i = 0; i < 8; ++i) {
    int m = bm + (i >> 2) * 64 + ty * 4 + (i & 3);
#pragma unroll
    for (int j = 0; j < 8; ++j) {
      int n = bn + (j >> 2) * 64 + tx * 4 + (j & 3);
      float v = acc[i][j];
      if (EPI == 1) {
        if (n < 256) C[(size_t)m * 256 + n] = v;
        else C2[(size_t)m * 256 + (n - 256)] = v / (1.0f + expf(-v));
      } else if (EPI == 2) {
        C[(size_t)m * N + n] = v + addsrc[(size_t)m * N + n];
      } else if (EPI == 3) {
        float u = v + bias[n];
        C[(size_t)m * N + n] =
            0.5f * u * (1.0f + tanhf(0.7978845608028654f * (u + 0.044715f * u * u * u)));
      } else if (EPI == 4) {
        C[(size_t)m * N + n] = v + bias[n] + addsrc[(size_t)m * N + n];
      }
    }
  }
}

// ---------------- depthwise conv3x3 + silu + x_dbl/dts/deltaA/feat ----------------
// feat/dA written TRANSPOSED: [b][group=d>>2][node][d&3]
__global__ __launch_bounds__(256) void convfeat_kernel(
    const float* __restrict__ xcpre, const float* __restrict__ cw,
    const float* __restrict__ xw, const float* __restrict__ dtw,
    const float* __restrict__ dtb, const float* __restrict__ alogs,
    float* __restrict__ xs, float* __restrict__ dAt, float* __restrict__ featt,
    float* __restrict__ Cs, float* __restrict__ ssq) {
  int m = blockIdx.x;
  int d = threadIdx.x;
  int l = m & (LB - 1), b = m >> 12;
  int r = l >> 6, c = l & 63;
  float acc = 0.f;
#pragma unroll
  for (int ky = 0; ky < 3; ++ky) {
    int rr = r + ky - 1;
    if (rr < 0 || rr > 63) continue;
#pragma unroll
    for (int kx = 0; kx < 3; ++kx) {
      int cc = c + kx - 1;
      if (cc < 0 || cc > 63) continue;
      int ml = (b << 12) + (rr << 6) + cc;
      acc += xcpre[(size_t)ml * 256 + d] * cw[d * 9 + ky * 3 + kx];
    }
  }
  float xv = acc / (1.0f + expf(-acc));        // silu
  xs[(size_t)m * 256 + d] = xv;
  float p[11];
#pragma unroll
  for (int i = 0; i < 10; ++i) p[i] = xv * xw[i * 256 + d];
  p[10] = xv * xv;
  __shared__ float sm[4][11];
#pragma unroll
  for (int i = 0; i < 11; ++i) p[i] = warp_sum(p[i]);
  int wv = d >> 6;
  if ((d & 63) == 0) {
    for (int i = 0; i < 11; ++i) sm[wv][i] = p[i];
  }
  __syncthreads();
  float red[11];
#pragma unroll
  for (int i = 0; i < 11; ++i) red[i] = sm[0][i] + sm[1][i] + sm[2][i] + sm[3][i];
  float xdt = dtb[d];
#pragma unroll
  for (int rr2 = 0; rr2 < 8; ++rr2) xdt += red[rr2] * dtw[d * 8 + rr2];
  float sp = fmaxf(xdt, 0.f) + log1pf(expf(-fabsf(xdt)));   // softplus
  float As_ = -expf(alogs[d]);
  size_t tidx = ((size_t)(b * 64 + (d >> 2)) * 4096 + l) * 4 + (d & 3);
  dAt[tidx]   = expf(sp * As_);
  featt[tidx] = sp * red[8] * xv;
  if (d == 0) { Cs[m] = red[9]; ssq[m] = red[10]; }
}

// ---------------- grid edge weights wr/wd ----------------
__global__ __launch_bounds__(256) void gridw_kernel(
    const float* __restrict__ xs, const float* __restrict__ ssq,
    float* __restrict__ wrg, float* __restrict__ wdg) {
  int m = blockIdx.x, d = threadIdx.x;
  int l = m & (LB - 1);
  int r = l >> 6, c = l & 63;
  float a = xs[(size_t)m * 256 + d];
  float br = (c < 63) ? xs[(size_t)(m + 1) * 256 + d] : 0.f;
  float bd = (r < 63) ? xs[(size_t)(m + 64) * 256 + d] : 0.f;
  float s1 = warp_sum(a * br);
  float s2 = warp_sum(a * bd);
  __shared__ float sm[4][2];
  int wv = d >> 6;
  if ((d & 63) == 0) { sm[wv][0] = s1; sm[wv][1] = s2; }
  __syncthreads();
  if (d == 0) {
    float dotr = sm[0][0] + sm[1][0] + sm[2][0] + sm[3][0];
    float dotd = sm[0][1] + sm[1][1] + sm[2][1] + sm[3][1];
    float na = sqrtf(ssq[m]);
    float wrv = BIGF, wdv = BIGF;
    if (c < 63) { float den = fmaxf(na * sqrtf(ssq[m + 1]), 1e-8f);  wrv = expf(-(dotr / den)); }
    if (r < 63) { float den = fmaxf(na * sqrtf(ssq[m + 64]), 1e-8f); wdv = expf(-(dotd / den)); }
    wrg[m] = wrv; wdg[m] = wdv;
  }
}

// ---------------- Boruvka MST + Euler-tour rooting (O(log V)) + levels ----------------
// Outputs position-space arrays for the scan:
//   levn16[pos] = node | childmask<<12   (mask bits: 1=N,2=W,4=E,8=S)
//   parn16[pos] = par[node]
// Directions: 0=N(-64), 1=W(-1), 2=E(+1), 3=S(+64); rev(d)=3-d.
__global__ __launch_bounds__(1024) void mst_kernel(
    const float* __restrict__ wr_g, const float* __restrict__ wd_g,
    unsigned short* __restrict__ levn16_g, unsigned short* __restrict__ parn16_g,
    int* __restrict__ levs_g) {
  __shared__ int pool[24592];          // 98.4 KB, phase-overlaid
  __shared__ unsigned char flagR[4096];
  __shared__ unsigned char flagD[4096];
  __shared__ int ncomp_s;
  __shared__ int wred[16];
  int b = blockIdx.x, tid = threadIdx.x;
  // ---- phase A layout (Boruvka) ----
  float* wrs = (float*)pool;
  float* wds = (float*)(pool + 4096);
  int* comp = pool + 8192;
  int* lnk  = pool + 12288;
  unsigned int* bestw = (unsigned int*)(pool + 16384);
  int* beste = pool + 20480;
  const float* wrb = wr_g + b * 4096;
  const float* wdb = wd_g + b * 4096;
  for (int k = 0; k < 4; ++k) {
    int i = tid + k * 1024;
    wrs[i] = wrb[i]; wds[i] = wdb[i];
    comp[i] = i; flagR[i] = 0; flagD[i] = 0;
  }
  __syncthreads();
  for (int phase = 0; phase < 13; ++phase) {
    for (int k = 0; k < 4; ++k) {
      int c = tid + k * 1024;
      bestw[c] = 0xFFFFFFFFu; beste[c] = 0x7FFFFFFF; lnk[c] = c;
    }
    if (tid == 0) ncomp_s = 0;
    __syncthreads();
    // pass A: per-component min weight
    for (int k = 0; k < 8; ++k) {
      int e = tid + k * 1024;
      int v = e & 4095;
      bool isR = e < 4096;
      int c = v & 63, r = v >> 6;
      bool valid = isR ? (c < 63) : (r < 63);
      if (valid) {
        int u = isR ? v + 1 : v + 64;
        int ca = comp[v], cb = comp[u];
        if (ca != cb) {
          unsigned wbits = __float_as_uint(isR ? wrs[v] : wds[v]);
          atomicMin(&bestw[ca], wbits);
          atomicMin(&bestw[cb], wbits);
        }
      }
    }
    __syncthreads();
    // pass B: min edge id among tied-min weights
    for (int k = 0; k < 8; ++k) {
      int e = tid + k * 1024;
      int v = e & 4095;
      bool isR = e < 4096;
      int c = v & 63, r = v >> 6;
      bool valid = isR ? (c < 63) : (r < 63);
      if (valid) {
        int u = isR ? v + 1 : v + 64;
        int ca = comp[v], cb = comp[u];
        if (ca != cb) {
          unsigned wbits = __float_as_uint(isR ? wrs[v] : wds[v]);
          if (wbits == bestw[ca]) atomicMin(&beste[ca], e);
          if (wbits == bestw[cb]) atomicMin(&beste[cb], e);
        }
      }
    }
    __syncthreads();
    // hook + flag chosen edges
    for (int k = 0; k < 4; ++k) {
      int cc = tid + k * 1024;
      int e = beste[cc];
      if (e != 0x7FFFFFFF) {
        int v = e & 4095;
        bool isR = e < 4096;
        int u = isR ? v + 1 : v + 64;
        if (isR) flagR[v] = 1; else flagD[v] = 1;
        int ca = comp[v], cb = comp[u];
        lnk[cc] = (ca == cc) ? cb : ca;
      }
    }
    __syncthreads();
    // break 2-cycles
    for (int k = 0; k < 4; ++k) {
      int cc = tid + k * 1024;
      int l = lnk[cc];
      if (l != cc && lnk[l] == cc && cc < l) lnk[cc] = cc;
    }
    __syncthreads();
    // pointer jumping
    for (int it = 0; it < 12; ++it) {
      for (int k = 0; k < 4; ++k) {
        int cc = tid + k * 1024;
        lnk[cc] = lnk[lnk[cc]];
      }
      __syncthreads();
    }
    // relabel + count roots
    for (int k = 0; k < 4; ++k) {
      int i = tid + k * 1024;
      comp[i] = lnk[comp[i]];
      if (comp[i] == i) atomicAdd(&ncomp_s, 1);
    }
    __syncthreads();
    if (ncomp_s <= 1) break;
    __syncthreads();
  }
  // ---- phase B layout (Euler tour; overlays dead Boruvka arrays) ----
  unsigned short* nxt = (unsigned short*)pool;        // [16400]
  short*          dsv = (short*)(pool + 8200);        // [16400]
  int* par = pool + 16400;                            // [4096]
  int* dep = pool + 20496;                            // [4096]
  const int NIL = 16384;
  unsigned short rn[16];
  int rd[16];
  int validm = 0;
  // pass-1 build: next pointers + unit weights; init par/dep
  for (int k = 0; k < 4; ++k) { int i = tid + k * 1024; par[i] = 0; dep[i] = 0; }
#pragma unroll
  for (int k = 0; k < 16; ++k) {
    int a = tid + k * 1024;
    int u = a >> 2, d = a & 3;
    int c = u & 63, r = u >> 6;
    int mu = 0;
    if (r > 0  && flagD[u - 64]) mu |= 1;
    if (c > 0  && flagR[u - 1])  mu |= 2;
    if (c < 63 && flagR[u])      mu |= 4;
    if (r < 63 && flagD[u])      mu |= 8;
    unsigned short nx = NIL; short dv = 0;
    if (mu & (1 << d)) {
      validm |= 1 << k;
      int v = u + ((d == 0) ? -64 : (d == 1) ? -1 : (d == 2) ? 1 : 64);
      int cv = v & 63, rv = v >> 6;
      int mv = 0;
      if (rv > 0  && flagD[v - 64]) mv |= 1;
      if (cv > 0  && flagR[v - 1])  mv |= 2;
      if (cv < 63 && flagR[v])      mv |= 4;
      if (rv < 63 && flagD[v])      mv |= 8;
      int din = 3 - d;
      int hi = mv >> (din + 1);
      int dn = hi ? (din + __ffs(hi)) : (__ffs(mv) - 1);
      int nxv = v * 4 + dn;
      int m0 = (flagR[0] ? 4 : 0) | (flagD[0] ? 8 : 0);
      int a0 = __ffs(m0) - 1;                 // start arc (root node 0)
      if (v == 0 && nxv == a0) nxv = NIL;     // break circuit before start
      nx = (unsigned short)nxv;
      dv = 1;
    }
    nxt[a] = nx; dsv[a] = dv;
    rn[k] = nx; rd[k] = dv;
  }
  if (tid == 0) { nxt[NIL] = NIL; dsv[NIL] = 0; }
  __syncthreads();
  // pass-1 list ranking: dsv -> suffix length (pos smaller <=> dsv larger)
#pragma unroll 1
  for (int it = 0; it < 13; ++it) {
    unsigned short nn[16]; short nd[16];
#pragma unroll
    for (int k = 0; k < 16; ++k) { nn[k] = nxt[rn[k]]; nd[k] = dsv[rn[k]]; }
    __syncthreads();
#pragma unroll
    for (int k = 0; k < 16; ++k) {
      int a = tid + k * 1024;
      rd[k] += nd[k];
      rn[k] = nn[k];
      nxt[a] = rn[k]; dsv[a] = (short)rd[k];
    }
    __syncthreads();
  }
  // orientation: par[v] = u iff arc u->v earlier than v->u (dsv larger)
#pragma unroll
  for (int k = 0; k < 16; ++k) if (validm & (1 << k)) {
    int a = tid + k * 1024;
    int u = a >> 2, d = a & 3;
    int v = u + ((d == 0) ? -64 : (d == 1) ? -1 : (d == 2) ? 1 : 64);
    int rb = v * 4 + (3 - d);
    if (rd[k] > (int)dsv[rb]) par[v] = u;
  }
  __syncthreads();
  // pass-2 build: same next pointers, weights +1 (down) / -1 (up)
#pragma unroll
  for (int k = 0; k < 16; ++k) {
    int a = tid + k * 1024;
    int u = a >> 2, d = a & 3;
    unsigned short nx = NIL; short dv = 0;
    if (validm & (1 << k)) {
      int v = u + ((d == 0) ? -64 : (d == 1) ? -1 : (d == 2) ? 1 : 64);
      int cv = v & 63, rv = v >> 6;
      int mv = 0;
      if (rv > 0  && flagD[v - 64]) mv |= 1;
      if (cv > 0  && flagR[v - 1])  mv |= 2;
      if (cv < 63 && flagR[v])      mv |= 4;
      if (rv < 63 && flagD[v])      mv |= 8;
      int din = 3 - d;
      int hi = mv >> (din + 1);
      int dn = hi ? (din + __ffs(hi)) : (__ffs(mv) - 1);
      int nxv = v * 4 + dn;
      int m0 = (flagR[0] ? 4 : 0) | (flagD[0] ? 8 : 0);
      int a0 = __ffs(m0) - 1;
      if (v == 0 && nxv == a0) nxv = NIL;
      nx = (unsigned short)nxv;
      dv = (par[v] == u) ? (short)1 : (short)-1;
    }
    nxt[a] = nx; dsv[a] = dv;
    rn[k] = nx; rd[k] = dv;
  }
  __syncthreads();
  // pass-2 weighted ranking: dsv -> suffix sum S(a)
#pragma unroll 1
  for (int it = 0; it < 13; ++it) {
    unsigned short nn[16]; short nd[16];
#pragma unroll
    for (int k = 0; k < 16; ++k) { nn[k] = nxt[rn[k]]; nd[k] = dsv[rn[k]]; }
    __syncthreads();
#pragma unroll
    for (int k = 0; k < 16; ++k) {
      int a = tid + k * 1024;
      rd[k] += nd[k];
      rn[k] = nn[k];
      nxt[a] = rn[k]; dsv[a] = (short)rd[k];
    }
    __syncthreads();
  }
  // depth: dep[v] = 1 - S(par->v)
#pragma unroll
  for (int k = 0; k < 16; ++k) if (validm & (1 << k)) {
    int a = tid + k * 1024;
    int u = a >> 2, d = a & 3;
    int v = u + ((d == 0) ? -64 : (d == 1) ? -1 : (d == 2) ? 1 : 64);
    if (par[v] == u) dep[v] = 1 - rd[k];
  }
  __syncthreads();
  // ---- max depth ----
  int md = 0;
  for (int k = 0; k < 4; ++k) md = max(md, dep[tid + k * 1024]);
#pragma unroll
  for (int off = 32; off; off >>= 1) md = max(md, __shfl_xor(md, off));
  if ((tid & 63) == 0) wred[tid >> 6] = md;
  __syncthreads();
  if (tid == 0) {
    int m = 0;
    for (int i = 0; i < 16; ++i) m = max(m, wred[i]);
    wred[0] = m;
  }
  __syncthreads();
  int maxd = wred[0];
  __syncthreads();
  // ---- histogram + exclusive prefix over depth buckets (cnt/offs overlay dead nxt/dsv) ----
  int* cnt  = pool;
  int* offs = pool + 4096;
  for (int k = 0; k < 4; ++k) cnt[tid + k * 1024] = 0;
  __syncthreads();
  for (int k = 0; k < 4; ++k) atomicAdd(&cnt[dep[tid + k * 1024]], 1);
  __syncthreads();
  int base4 = tid * 4;
  int c0 = cnt[base4], c1 = cnt[base4 + 1], c2 = cnt[base4 + 2], c3 = cnt[base4 + 3];
  int tsum = c0 + c1 + c2 + c3;
  int lane = tid & 63, wid = tid >> 6;
  int iv = tsum;
  for (int off = 1; off < 64; off <<= 1) {
    int n = __shfl_up(iv, off);
    if (lane >= off) iv += n;
  }
  if (lane == 63) wred[wid] = iv;
  __syncthreads();
  if (tid == 0) {
    int acc = 0;
    for (int i = 0; i < 16; ++i) { int t = wred[i]; wred[i] = acc; acc += t; }
  }
  __syncthreads();
  int excl = iv - tsum + wred[wid];
  offs[base4]     = excl;
  offs[base4 + 1] = excl + c0;
  offs[base4 + 2] = excl + c0 + c1;
  offs[base4 + 3] = excl + c0 + c1 + c2;
  __syncthreads();
  for (int idx = tid; idx <= maxd; idx += 1024) levs_g[b * LSP + idx] = offs[idx];
  if (tid == 0) {
    levs_g[b * LSP + maxd + 1] = 4096;
    levs_g[b * LSP + 4098] = maxd + 1;
  }
  __syncthreads();   // levs_g copy must finish reading offs before scatter mutates it
  // ---- scatter nodes by level: node|childmask and parent node, by position ----
  for (int k = 0; k < 4; ++k) {
    int v2 = tid + k * 1024;
    int pos = atomicAdd(&offs[dep[v2]], 1);
    int c = v2 & 63, r = v2 >> 6;
    unsigned msk = 0;
    if (r > 0  && par[v2 - 64] == v2) msk |= 1;
    if (c > 0  && par[v2 - 1]  == v2) msk |= 2;
    if (c < 63 && par[v2 + 1]  == v2) msk |= 4;
    if (r < 63 && par[v2 + 64] == v2) msk |= 8;
    levn16_g[b * 4096 + pos] = (unsigned short)(v2 | (msk << 12));
    parn16_g[b * 4096 + pos] = (unsigned short)par[v2];
  }
}

// ---------------- single-wave LDS-resident tree scan, transposed coalesced I/O ----------------
// 512 blocks x 64 threads; block bid -> (batch bid>>6, channel-group bid&63).
// featt/dAt layout: [(b*64+cg)*4096 + node] float4 (4 ch) -> contiguous 64KB per block.
// LDS planes: pr2[ch*4097 + node] = {bl, el}; plane stride 4097 float2 breaks bank alignment.
__global__ __launch_bounds__(64) void scan_kernel(
    float* __restrict__ buft, const float* __restrict__ ewt,
    const unsigned short* __restrict__ levn16_g,
    const unsigned short* __restrict__ parn16_g,
    const int* __restrict__ levs_g) {
  __shared__ float pr[32776];            // 4 planes x 4097 float2
  __shared__ unsigned int topo[4096];    // levn16 | parn16<<16, by position
  __shared__ unsigned short lvs[4104];
  int bid = blockIdx.x;
  int b = bid >> 6;
  int cg = bid & 63;
  int lane = threadIdx.x;
  int nlev = levs_g[b * LSP + 4098];
  size_t tbase = (size_t)(b * 64 + cg) * 4096;
  float2* pr2 = reinterpret_cast<float2*>(pr);
  // ---- stage (fully coalesced) ----
  const float4* bt4 = reinterpret_cast<const float4*>(buft) + tbase;
  const float4* et4 = reinterpret_cast<const float4*>(ewt) + tbase;
  for (int n = lane; n < 4096; n += 64) {
    float4 bv = bt4[n];
    float4 ev = et4[n];
    pr2[0 * 4097 + n] = make_float2(bv.x, ev.x);
    pr2[1 * 4097 + n] = make_float2(bv.y, ev.y);
    pr2[2 * 4097 + n] = make_float2(bv.z, ev.z);
    pr2[3 * 4097 + n] = make_float2(bv.w, ev.w);
  }
  const unsigned int* lv32 = reinterpret_cast<const unsigned int*>(levn16_g + b * 4096);
  const unsigned int* pn32 = reinterpret_cast<const unsigned int*>(parn16_g + b * 4096);
  for (int i2 = lane; i2 < 2048; i2 += 64) {
    unsigned int a = lv32[i2], p = pn32[i2];
    topo[2 * i2]     = (a & 0xFFFFu) | (p << 16);
    topo[2 * i2 + 1] = (a >> 16) | (p & 0xFFFF0000u);
  }
  for (int i = lane; i <= nlev; i += 64) lvs[i] = (unsigned short)levs_g[b * LSP + i];
  __syncthreads();
  int ch = lane & 3;
  int slot = lane >> 2;            // 0..15
  int cpl = ch * 4097;             // plane offset in float2
  // ---- up: parent gathers children via childmask (order N,W,E,S) ----
  {
    int s = lvs[nlev - 2], e = lvs[nlev - 1];
    int jn = s + slot;
    unsigned int pkn = topo[jn & 4095];
    for (int lev = nlev - 2; lev >= 0; --lev) {
      int ce = e;
      int j = jn;
      unsigned int pk = pkn;
      if (lev > 0) {                       // prefetch next level
        e = s; s = lvs[lev - 1];
        jn = s + slot;
        pkn = topo[jn & 4095];
      }
      bool first = true;
      while (j < ce) {
        if (!first) pk = topo[j];
        first = false;
        int p = pk & 4095;
        unsigned msk = (pk >> 12) & 15u;
        float acc = pr[(cpl + p) * 2];
        if (msk & 1) { float2 cp = pr2[cpl + p - 64]; acc += cp.y * cp.x; }
        if (msk & 2) { float2 cp = pr2[cpl + p - 1];  acc += cp.y * cp.x; }
        if (msk & 4) { float2 cp = pr2[cpl + p + 1];  acc += cp.y * cp.x; }
        if (msk & 8) { float2 cp = pr2[cpl + p + 64]; acc += cp.y * cp.x; }
        pr[(cpl + p) * 2] = acc;
        j += 16;
      }
      __builtin_amdgcn_wave_barrier();     // pin ordering between levels
    }
  }
  __builtin_amdgcn_wave_barrier();
  // ---- down: out[v] = up[v] + w*(out[p] - w*up[v]) ----
  if (nlev > 1) {
    int s = lvs[1], e = lvs[2];
    int jn = s + slot;
    unsigned int pkn = topo[jn & 4095];
    for (int lev = 1; lev < nlev; ++lev) {
      int ce = e;
      int j = jn;
      unsigned int pk = pkn;
      if (lev + 1 < nlev) {
        s = e; e = lvs[lev + 2];
        jn = s + slot;
        pkn = topo[jn & 4095];
      }
      bool first = true;
      while (j < ce) {
        if (!first) pk = topo[j];
        first = false;
        int v = pk & 4095;
        int p = (pk >> 16) & 4095;
        float2 self = pr2[cpl + v];          // {bl, el}
        float pb = pr[(cpl + p) * 2];
        float w = self.y, uv = self.x;
        pr[(cpl + v) * 2] = uv + w * (pb - w * uv);
        j += 16;
      }
      __builtin_amdgcn_wave_barrier();
    }
  }
  __syncthreads();
  // ---- write back (coalesced) ----
  float4* bw4 = reinterpret_cast<float4*>(buft) + tbase;
  for (int n = lane; n < 4096; n += 64) {
    float2 c0 = pr2[0 * 4097 + n];
    float2 c1 = pr2[1 * 4097 + n];
    float2 c2 = pr2[2 * 4097 + n];
    float2 c3 = pr2[3 * 4097 + n];
    bw4[n] = make_float4(c0.x, c1.x, c2.x, c3.x);
  }
}

// ---------------- post-scan: LN(d=256) -> *Cs + ds*xs -> LN -> *z ----------------
// buft is transposed: fo = buft[((b*64 + d/4)*4096 + l)*4 + d%4]
__global__ __launch_bounds__(256) void post_kernel(
    const float* __restrict__ buft, const float* __restrict__ Cs,
    const float* __restrict__ xs, const float* __restrict__ ds,
    const float* __restrict__ hng, const float* __restrict__ hnb,
    const float* __restrict__ ong, const float* __restrict__ onb,
    float* __restrict__ zya) {
  int m = blockIdx.x, d = threadIdx.x;
  int b = m >> 12, l = m & (LB - 1);
  size_t idx = (size_t)m * 256 + d;
  float fo = buft[((size_t)(b * 64 + (d >> 2)) * 4096 + l) * 4 + (d & 3)];
  float mu = block_sum256(fo) * (1.f / 256.f);
  float dv = fo - mu;
  float var = block_sum256(dv * dv) * (1.f / 256.f);
  float ho = dv * (1.0f / sqrtf(var + 1e-5f)) * hng[d] + hnb[d];
  float y = ho * Cs[m] + ds[d] * xs[idx];
  float mu2 = block_sum256(y) * (1.f / 256.f);
  float dy = y - mu2;
  float var2 = block_sum256(dy * dy) * (1.f / 256.f);
  float y2 = dy * (1.0f / sqrtf(var2 + 1e-5f)) * ong[d] + onb[d];
  zya[idx] = y2 * zya[idx];     // ya = y * z (in place over z)
}

// ---------------- launcher ----------------
extern "C" void kernel_launch(void* const* d_in, const int* in_sizes, int n_in,
                              void* d_out, int out_size, void* d_ws, size_t ws_size,
                              hipStream_t stream) {
  (void)in_sizes; (void)n_in; (void)out_size; (void)ws_size;
  const float* x      = (const float*)d_in[0];
  const float* ln1g   = (const float*)d_in[1];
  const float* ln1b   = (const float*)d_in[2];
  const float* ln2g   = (const float*)d_in[3];
  const float* ln2b   = (const float*)d_in[4];
  const float* w_in   = (const float*)d_in[5];
  const float* conv_w = (const float*)d_in[6];
  const float* xw     = (const float*)d_in[7];
  const float* dtw    = (const float*)d_in[8];
  const float* dtb    = (const float*)d_in[9];
  const float* alogs  = (const float*)d_in[10];
  const float* dsv    = (const float*)d_in[11];
  const float* hng    = (const float*)d_in[12];
  const float* hnb    = (const float*)d_in[13];
  const float* ong    = (const float*)d_in[14];
  const float* onb    = (const float*)d_in[15];
  const float* w_out  = (const float*)d_in[16];
  const float* mw1    = (const float*)d_in[17];
  const float* mb1    = (const float*)d_in[18];
  const float* mw2    = (const float*)d_in[19];
  const float* mb2    = (const float*)d_in[20];

  char* ws = (char*)d_ws;
  float* h    = (float*)(ws + 0);            // 16MB (h, later x1)
  float* z    = (float*)(ws + 16777216);     // 33.5MB (z, later ya in-place)
  float* xcp  = (float*)(ws + 50331648);     // 33.5MB (xc_pre, later h2)
  float* xs   = (float*)(ws + 83886080);     // 33.5MB
  float* dAt  = (float*)(ws + 117440512);    // 33.5MB transposed deltaA
  float* featt= (float*)(ws + 150994944);    // 33.5MB transposed feat -> scan buf
  float* Cs   = (float*)(ws + 184549376);
  float* ssq  = (float*)(ws + 184680448);
  float* wr   = (float*)(ws + 184811520);
  float* wd   = (float*)(ws + 184942592);
  unsigned short* levn16 = (unsigned short*)(ws + 185073664);   // 64KB
  unsigned short* parn16 = (unsigned short*)(ws + 185204736);   // 64KB
  int*   levs = (int*)(ws + 185335808);
  float* midg = xs;      // 67MB spans xs+dAt (both dead by then)
  float* x1   = h;
  float* h2   = xcp;

  ln128_kernel<<<MROWS / 4, 256, 0, stream>>>(x, ln1g, ln1b, h, 1e-6f);
  gemm_kernel<1><<<dim3(4, 256), 256, 0, stream>>>(h, w_in, xcp, z, nullptr, nullptr,
                                                   MROWS, 512, 128);
  convfeat_kernel<<<MROWS, 256, 0, stream>>>(xcp, conv_w, xw, dtw, dtb, alogs,
                                             xs, dAt, featt, Cs, ssq);
  gridw_kernel<<<MROWS, 256, 0, stream>>>(xs, ssq, wr, wd);
  mst_kernel<<<NB, 1024, 0, stream>>>(wr, wd, levn16, parn16, levs);
  scan_kernel<<<512, 64, 0, stream>>>(featt, dAt, levn16, parn16, levs);
  post_kernel<<<MROWS, 256, 0, stream>>>(featt, Cs, xs, dsv, hng, hnb, ong, onb, z);
  gemm_kernel<2><<<dim3(1, 256), 256, 0, stream>>>(z, w_out, x1, nullptr, nullptr, x,
                                                   MROWS, 128, 256);
  ln128_kernel<<<MROWS / 4, 256, 0, stream>>>(x1, ln2g, ln2b, h2, 1e-6f);
  gemm_kernel<3><<<dim3(4, 256), 256, 0, stream>>>(h2, mw1, midg, nullptr, mb1, nullptr,
                                                   MROWS, 512, 128);
  gemm_kernel<4><<<dim3(1, 256), 256, 0, stream>>>(midg, mw2, (float*)d_out, nullptr,
                                                   mb2, x1, MROWS, 128, 512);
}

// Round 12
// 874.386 us; speedup vs baseline: 1.1811x; 1.1811x over previous
//
#include <hip/hip_runtime.h>
#include <hip/hip_bf16.h>
#include <cstdint>

#define BIGF 1e30f
constexpr int LB   = 4096;           // L = H*W
constexpr int NB   = 8;              // batch
constexpr int MROWS = NB * LB;       // 32768 pixel rows
constexpr int LSP  = 4104;           // level-start stride per batch

// ---------------- helpers ----------------
__device__ __forceinline__ float warp_sum(float v) {
#pragma unroll
  for (int off = 32; off; off >>= 1) v += __shfl_xor(v, off);
  return v;
}

__device__ __forceinline__ float block_sum256(float v) {
  __shared__ float sm[4];
  v = warp_sum(v);
  __syncthreads();
  if ((threadIdx.x & 63) == 0) sm[threadIdx.x >> 6] = v;
  __syncthreads();
  return sm[0] + sm[1] + sm[2] + sm[3];
}

// ---------------- LayerNorm over last dim 128 ----------------
__global__ __launch_bounds__(256) void ln128_kernel(
    const float* __restrict__ X, const float* __restrict__ g,
    const float* __restrict__ bb, float* __restrict__ O, float eps) {
  int wave = threadIdx.x >> 6, lane = threadIdx.x & 63;
  int row = blockIdx.x * 4 + wave;
  const float* xr = X + (size_t)row * 128;
  float x0 = xr[lane], x1 = xr[lane + 64];
  float mu = warp_sum(x0 + x1) * (1.0f / 128.0f);
  float d0 = x0 - mu, d1 = x1 - mu;
  float var = warp_sum(d0 * d0 + d1 * d1) * (1.0f / 128.0f);
  float s = 1.0f / sqrtf(var + eps);
  float* orow = O + (size_t)row * 128;
  orow[lane]      = d0 * s * g[lane]      + bb[lane];
  orow[lane + 64] = d1 * s * g[lane + 64] + bb[lane + 64];
}

// ---------------- generic f32 GEMM: C = A[M,K] @ W[N,K]^T, fused epilogues ----------------
// (round-10 64x64 config — 128x128 regressed gemm2/4 via 1-block/CU grids)
template<int EPI>
__global__ __launch_bounds__(256) void gemm_kernel(
    const float* __restrict__ A, const float* __restrict__ W,
    float* __restrict__ C, float* __restrict__ C2,
    const float* __restrict__ bias, const float* __restrict__ addsrc,
    int M, int N, int K) {
  __shared__ float As[32][68];
  __shared__ float Bs[32][68];
  int t = threadIdx.x;
  int tx = t & 15, ty = t >> 4;
  int bm = blockIdx.y * 64, bn = blockIdx.x * 64;
  float acc[4][4] = {};
  for (int k0 = 0; k0 < K; k0 += 32) {
#pragma unroll
    for (int hh = 0; hh < 2; ++hh) {
      int q = t + hh * 256;
      int r = q >> 3, kc = q & 7;
      float4 a4 = reinterpret_cast<const float4*>(A + (size_t)(bm + r) * K + k0)[kc];
      float4 b4 = reinterpret_cast<const float4*>(W + (size_t)(bn + r) * K + k0)[kc];
      As[kc * 4 + 0][r] = a4.x; As[kc * 4 + 1][r] = a4.y;
      As[kc * 4 + 2][r] = a4.z; As[kc * 4 + 3][r] = a4.w;
      Bs[kc * 4 + 0][r] = b4.x; Bs[kc * 4 + 1][r] = b4.y;
      Bs[kc * 4 + 2][r] = b4.z; Bs[kc * 4 + 3][r] = b4.w;
    }
    __syncthreads();
#pragma unroll
    for (int kk = 0; kk < 32; ++kk) {
      float4 av = *reinterpret_cast<const float4*>(&As[kk][ty * 4]);
      float4 bv = *reinterpret_cast<const float4*>(&Bs[kk][tx * 4]);
      float aa[4] = {av.x, av.y, av.z, av.w};
      float bbv[4] = {bv.x, bv.y, bv.z, bv.w};
#pragma unroll
      for (int i = 0; i < 4; ++i)
#pragma unroll
        for (int j = 0; j < 4; ++j) acc[i][j] += aa[i] * bbv[j];
    }
    __syncthreads();
  }
#pragma unroll
  for (int i = 0; i < 4; ++i) {
    int m = bm + ty * 4 + i;
#pragma unroll
    for (int j = 0; j < 4; ++j) {
      int n = bn + tx * 4 + j;
      float v = acc[i][j];
      if (EPI == 1) {
        if (n < 256) C[(size_t)m * 256 + n] = v;
        else C2[(size_t)m * 256 + (n - 256)] = v / (1.0f + expf(-v));
      } else if (EPI == 2) {
        C[(size_t)m * N + n] = v + addsrc[(size_t)m * N + n];
      } else if (EPI == 3) {
        float u = v + bias[n];
        C[(size_t)m * N + n] =
            0.5f * u * (1.0f + tanhf(0.7978845608028654f * (u + 0.044715f * u * u * u)));
      } else if (EPI == 4) {
        C[(size_t)m * N + n] = v + bias[n] + addsrc[(size_t)m * N + n];
      }
    }
  }
}

// ---------------- depthwise conv3x3 + silu + x_dbl/dts/deltaA/feat ----------------
// feat/dA written TRANSPOSED: [b][group=d>>2][node][d&3]
__global__ __launch_bounds__(256) void convfeat_kernel(
    const float* __restrict__ xcpre, const float* __restrict__ cw,
    const float* __restrict__ xw, const float* __restrict__ dtw,
    const float* __restrict__ dtb, const float* __restrict__ alogs,
    float* __restrict__ xs, float* __restrict__ dAt, float* __restrict__ featt,
    float* __restrict__ Cs, float* __restrict__ ssq) {
  int m = blockIdx.x;
  int d = threadIdx.x;
  int l = m & (LB - 1), b = m >> 12;
  int r = l >> 6, c = l & 63;
  float acc = 0.f;
#pragma unroll
  for (int ky = 0; ky < 3; ++ky) {
    int rr = r + ky - 1;
    if (rr < 0 || rr > 63) continue;
#pragma unroll
    for (int kx = 0; kx < 3; ++kx) {
      int cc = c + kx - 1;
      if (cc < 0 || cc > 63) continue;
      int ml = (b << 12) + (rr << 6) + cc;
      acc += xcpre[(size_t)ml * 256 + d] * cw[d * 9 + ky * 3 + kx];
    }
  }
  float xv = acc / (1.0f + expf(-acc));        // silu
  xs[(size_t)m * 256 + d] = xv;
  float p[11];
#pragma unroll
  for (int i = 0; i < 10; ++i) p[i] = xv * xw[i * 256 + d];
  p[10] = xv * xv;
  __shared__ float sm[4][11];
#pragma unroll
  for (int i = 0; i < 11; ++i) p[i] = warp_sum(p[i]);
  int wv = d >> 6;
  if ((d & 63) == 0) {
    for (int i = 0; i < 11; ++i) sm[wv][i] = p[i];
  }
  __syncthreads();
  float red[11];
#pragma unroll
  for (int i = 0; i < 11; ++i) red[i] = sm[0][i] + sm[1][i] + sm[2][i] + sm[3][i];
  float xdt = dtb[d];
#pragma unroll
  for (int rr2 = 0; rr2 < 8; ++rr2) xdt += red[rr2] * dtw[d * 8 + rr2];
  float sp = fmaxf(xdt, 0.f) + log1pf(expf(-fabsf(xdt)));   // softplus
  float As_ = -expf(alogs[d]);
  size_t tidx = ((size_t)(b * 64 + (d >> 2)) * 4096 + l) * 4 + (d & 3);
  dAt[tidx]   = expf(sp * As_);
  featt[tidx] = sp * red[8] * xv;
  if (d == 0) { Cs[m] = red[9]; ssq[m] = red[10]; }
}

// ---------------- grid edge weights wr/wd ----------------
__global__ __launch_bounds__(256) void gridw_kernel(
    const float* __restrict__ xs, const float* __restrict__ ssq,
    float* __restrict__ wrg, float* __restrict__ wdg) {
  int m = blockIdx.x, d = threadIdx.x;
  int l = m & (LB - 1);
  int r = l >> 6, c = l & 63;
  float a = xs[(size_t)m * 256 + d];
  float br = (c < 63) ? xs[(size_t)(m + 1) * 256 + d] : 0.f;
  float bd = (r < 63) ? xs[(size_t)(m + 64) * 256 + d] : 0.f;
  float s1 = warp_sum(a * br);
  float s2 = warp_sum(a * bd);
  __shared__ float sm[4][2];
  int wv = d >> 6;
  if ((d & 63) == 0) { sm[wv][0] = s1; sm[wv][1] = s2; }
  __syncthreads();
  if (d == 0) {
    float dotr = sm[0][0] + sm[1][0] + sm[2][0] + sm[3][0];
    float dotd = sm[0][1] + sm[1][1] + sm[2][1] + sm[3][1];
    float na = sqrtf(ssq[m]);
    float wrv = BIGF, wdv = BIGF;
    if (c < 63) { float den = fmaxf(na * sqrtf(ssq[m + 1]), 1e-8f);  wrv = expf(-(dotr / den)); }
    if (r < 63) { float den = fmaxf(na * sqrtf(ssq[m + 64]), 1e-8f); wdv = expf(-(dotd / den)); }
    wrg[m] = wrv; wdg[m] = wdv;
  }
}

// ---------------- Boruvka MST + Euler-tour rooting (O(log V)) + levels ----------------
// Outputs position-space arrays for the scan:
//   levn16[pos] = node | childmask<<12   (mask bits: 1=N,2=W,4=E,8=S)
//   parn16[pos] = par[node]
// Directions: 0=N(-64), 1=W(-1), 2=E(+1), 3=S(+64); rev(d)=3-d.
__global__ __launch_bounds__(1024) void mst_kernel(
    const float* __restrict__ wr_g, const float* __restrict__ wd_g,
    unsigned short* __restrict__ levn16_g, unsigned short* __restrict__ parn16_g,
    int* __restrict__ levs_g) {
  __shared__ int pool[24592];          // 98.4 KB, phase-overlaid
  __shared__ unsigned char flagR[4096];
  __shared__ unsigned char flagD[4096];
  __shared__ int ncomp_s;
  __shared__ int wred[16];
  int b = blockIdx.x, tid = threadIdx.x;
  // ---- phase A layout (Boruvka) ----
  float* wrs = (float*)pool;
  float* wds = (float*)(pool + 4096);
  int* comp = pool + 8192;
  int* lnk  = pool + 12288;
  unsigned int* bestw = (unsigned int*)(pool + 16384);
  int* beste = pool + 20480;
  const float* wrb = wr_g + b * 4096;
  const float* wdb = wd_g + b * 4096;
  for (int k = 0; k < 4; ++k) {
    int i = tid + k * 1024;
    wrs[i] = wrb[i]; wds[i] = wdb[i];
    comp[i] = i; flagR[i] = 0; flagD[i] = 0;
  }
  __syncthreads();
  for (int phase = 0; phase < 13; ++phase) {
    for (int k = 0; k < 4; ++k) {
      int c = tid + k * 1024;
      bestw[c] = 0xFFFFFFFFu; beste[c] = 0x7FFFFFFF; lnk[c] = c;
    }
    if (tid == 0) ncomp_s = 0;
    __syncthreads();
    // pass A: per-component min weight
    for (int k = 0; k < 8; ++k) {
      int e = tid + k * 1024;
      int v = e & 4095;
      bool isR = e < 4096;
      int c = v & 63, r = v >> 6;
      bool valid = isR ? (c < 63) : (r < 63);
      if (valid) {
        int u = isR ? v + 1 : v + 64;
        int ca = comp[v], cb = comp[u];
        if (ca != cb) {
          unsigned wbits = __float_as_uint(isR ? wrs[v] : wds[v]);
          atomicMin(&bestw[ca], wbits);
          atomicMin(&bestw[cb], wbits);
        }
      }
    }
    __syncthreads();
    // pass B: min edge id among tied-min weights
    for (int k = 0; k < 8; ++k) {
      int e = tid + k * 1024;
      int v = e & 4095;
      bool isR = e < 4096;
      int c = v & 63, r = v >> 6;
      bool valid = isR ? (c < 63) : (r < 63);
      if (valid) {
        int u = isR ? v + 1 : v + 64;
        int ca = comp[v], cb = comp[u];
        if (ca != cb) {
          unsigned wbits = __float_as_uint(isR ? wrs[v] : wds[v]);
          if (wbits == bestw[ca]) atomicMin(&beste[ca], e);
          if (wbits == bestw[cb]) atomicMin(&beste[cb], e);
        }
      }
    }
    __syncthreads();
    // hook + flag chosen edges
    for (int k = 0; k < 4; ++k) {
      int cc = tid + k * 1024;
      int e = beste[cc];
      if (e != 0x7FFFFFFF) {
        int v = e & 4095;
        bool isR = e < 4096;
        int u = isR ? v + 1 : v + 64;
        if (isR) flagR[v] = 1; else flagD[v] = 1;
        int ca = comp[v], cb = comp[u];
        lnk[cc] = (ca == cc) ? cb : ca;
      }
    }
    __syncthreads();
    // break 2-cycles
    for (int k = 0; k < 4; ++k) {
      int cc = tid + k * 1024;
      int l = lnk[cc];
      if (l != cc && lnk[l] == cc && cc < l) lnk[cc] = cc;
    }
    __syncthreads();
    // pointer jumping
    for (int it = 0; it < 12; ++it) {
      for (int k = 0; k < 4; ++k) {
        int cc = tid + k * 1024;
        lnk[cc] = lnk[lnk[cc]];
      }
      __syncthreads();
    }
    // relabel + count roots
    for (int k = 0; k < 4; ++k) {
      int i = tid + k * 1024;
      comp[i] = lnk[comp[i]];
      if (comp[i] == i) atomicAdd(&ncomp_s, 1);
    }
    __syncthreads();
    if (ncomp_s <= 1) break;
    __syncthreads();
  }
  // ---- phase B layout (Euler tour; overlays dead Boruvka arrays) ----
  unsigned short* nxt = (unsigned short*)pool;        // [16400]
  short*          dsv = (short*)(pool + 8200);        // [16400]
  int* par = pool + 16400;                            // [4096]
  int* dep = pool + 20496;                            // [4096]
  const int NIL = 16384;
  unsigned short rn[16];
  int rd[16];
  int validm = 0;
  // pass-1 build: next pointers + unit weights; init par/dep
  for (int k = 0; k < 4; ++k) { int i = tid + k * 1024; par[i] = 0; dep[i] = 0; }
#pragma unroll
  for (int k = 0; k < 16; ++k) {
    int a = tid + k * 1024;
    int u = a >> 2, d = a & 3;
    int c = u & 63, r = u >> 6;
    int mu = 0;
    if (r > 0  && flagD[u - 64]) mu |= 1;
    if (c > 0  && flagR[u - 1])  mu |= 2;
    if (c < 63 && flagR[u])      mu |= 4;
    if (r < 63 && flagD[u])      mu |= 8;
    unsigned short nx = NIL; short dv = 0;
    if (mu & (1 << d)) {
      validm |= 1 << k;
      int v = u + ((d == 0) ? -64 : (d == 1) ? -1 : (d == 2) ? 1 : 64);
      int cv = v & 63, rv = v >> 6;
      int mv = 0;
      if (rv > 0  && flagD[v - 64]) mv |= 1;
      if (cv > 0  && flagR[v - 1])  mv |= 2;
      if (cv < 63 && flagR[v])      mv |= 4;
      if (rv < 63 && flagD[v])      mv |= 8;
      int din = 3 - d;
      int hi = mv >> (din + 1);
      int dn = hi ? (din + __ffs(hi)) : (__ffs(mv) - 1);
      int nxv = v * 4 + dn;
      int m0 = (flagR[0] ? 4 : 0) | (flagD[0] ? 8 : 0);
      int a0 = __ffs(m0) - 1;                 // start arc (root node 0)
      if (v == 0 && nxv == a0) nxv = NIL;     // break circuit before start
      nx = (unsigned short)nxv;
      dv = 1;
    }
    nxt[a] = nx; dsv[a] = dv;
    rn[k] = nx; rd[k] = dv;
  }
  if (tid == 0) { nxt[NIL] = NIL; dsv[NIL] = 0; }
  __syncthreads();
  // pass-1 list ranking: dsv -> suffix length (pos smaller <=> dsv larger)
#pragma unroll 1
  for (int it = 0; it < 13; ++it) {
    unsigned short nn[16]; short nd[16];
#pragma unroll
    for (int k = 0; k < 16; ++k) { nn[k] = nxt[rn[k]]; nd[k] = dsv[rn[k]]; }
    __syncthreads();
#pragma unroll
    for (int k = 0; k < 16; ++k) {
      int a = tid + k * 1024;
      rd[k] += nd[k];
      rn[k] = nn[k];
      nxt[a] = rn[k]; dsv[a] = (short)rd[k];
    }
    __syncthreads();
  }
  // orientation: par[v] = u iff arc u->v earlier than v->u (dsv larger)
#pragma unroll
  for (int k = 0; k < 16; ++k) if (validm & (1 << k)) {
    int a = tid + k * 1024;
    int u = a >> 2, d = a & 3;
    int v = u + ((d == 0) ? -64 : (d == 1) ? -1 : (d == 2) ? 1 : 64);
    int rb = v * 4 + (3 - d);
    if (rd[k] > (int)dsv[rb]) par[v] = u;
  }
  __syncthreads();
  // pass-2 build: same next pointers, weights +1 (down) / -1 (up)
#pragma unroll
  for (int k = 0; k < 16; ++k) {
    int a = tid + k * 1024;
    int u = a >> 2, d = a & 3;
    unsigned short nx = NIL; short dv = 0;
    if (validm & (1 << k)) {
      int v = u + ((d == 0) ? -64 : (d == 1) ? -1 : (d == 2) ? 1 : 64);
      int cv = v & 63, rv = v >> 6;
      int mv = 0;
      if (rv > 0  && flagD[v - 64]) mv |= 1;
      if (cv > 0  && flagR[v - 1])  mv |= 2;
      if (cv < 63 && flagR[v])      mv |= 4;
      if (rv < 63 && flagD[v])      mv |= 8;
      int din = 3 - d;
      int hi = mv >> (din + 1);
      int dn = hi ? (din + __ffs(hi)) : (__ffs(mv) - 1);
      int nxv = v * 4 + dn;
      int m0 = (flagR[0] ? 4 : 0) | (flagD[0] ? 8 : 0);
      int a0 = __ffs(m0) - 1;
      if (v == 0 && nxv == a0) nxv = NIL;
      nx = (unsigned short)nxv;
      dv = (par[v] == u) ? (short)1 : (short)-1;
    }
    nxt[a] = nx; dsv[a] = dv;
    rn[k] = nx; rd[k] = dv;
  }
  __syncthreads();
  // pass-2 weighted ranking: dsv -> suffix sum S(a)
#pragma unroll 1
  for (int it = 0; it < 13; ++it) {
    unsigned short nn[16]; short nd[16];
#pragma unroll
    for (int k = 0; k < 16; ++k) { nn[k] = nxt[rn[k]]; nd[k] = dsv[rn[k]]; }
    __syncthreads();
#pragma unroll
    for (int k = 0; k < 16; ++k) {
      int a = tid + k * 1024;
      rd[k] += nd[k];
      rn[k] = nn[k];
      nxt[a] = rn[k]; dsv[a] = (short)rd[k];
    }
    __syncthreads();
  }
  // depth: dep[v] = 1 - S(par->v)
#pragma unroll
  for (int k = 0; k < 16; ++k) if (validm & (1 << k)) {
    int a = tid + k * 1024;
    int u = a >> 2, d = a & 3;
    int v = u + ((d == 0) ? -64 : (d == 1) ? -1 : (d == 2) ? 1 : 64);
    if (par[v] == u) dep[v] = 1 - rd[k];
  }
  __syncthreads();
  // ---- max depth ----
  int md = 0;
  for (int k = 0; k < 4; ++k) md = max(md, dep[tid + k * 1024]);
#pragma unroll
  for (int off = 32; off; off >>= 1) md = max(md, __shfl_xor(md, off));
  if ((tid & 63) == 0) wred[tid >> 6] = md;
  __syncthreads();
  if (tid == 0) {
    int m = 0;
    for (int i = 0; i < 16; ++i) m = max(m, wred[i]);
    wred[0] = m;
  }
  __syncthreads();
  int maxd = wred[0];
  __syncthreads();
  // ---- histogram + exclusive prefix over depth buckets (cnt/offs overlay dead nxt/dsv) ----
  int* cnt  = pool;
  int* offs = pool + 4096;
  for (int k = 0; k < 4; ++k) cnt[tid + k * 1024] = 0;
  __syncthreads();
  for (int k = 0; k < 4; ++k) atomicAdd(&cnt[dep[tid + k * 1024]], 1);
  __syncthreads();
  int base4 = tid * 4;
  int c0 = cnt[base4], c1 = cnt[base4 + 1], c2 = cnt[base4 + 2], c3 = cnt[base4 + 3];
  int tsum = c0 + c1 + c2 + c3;
  int lane = tid & 63, wid = tid >> 6;
  int iv = tsum;
  for (int off = 1; off < 64; off <<= 1) {
    int n = __shfl_up(iv, off);
    if (lane >= off) iv += n;
  }
  if (lane == 63) wred[wid] = iv;
  __syncthreads();
  if (tid == 0) {
    int acc = 0;
    for (int i = 0; i < 16; ++i) { int t = wred[i]; wred[i] = acc; acc += t; }
  }
  __syncthreads();
  int excl = iv - tsum + wred[wid];
  offs[base4]     = excl;
  offs[base4 + 1] = excl + c0;
  offs[base4 + 2] = excl + c0 + c1;
  offs[base4 + 3] = excl + c0 + c1 + c2;
  __syncthreads();
  for (int idx = tid; idx <= maxd; idx += 1024) levs_g[b * LSP + idx] = offs[idx];
  if (tid == 0) {
    levs_g[b * LSP + maxd + 1] = 4096;
    levs_g[b * LSP + 4098] = maxd + 1;
  }
  __syncthreads();   // levs_g copy must finish reading offs before scatter mutates it
  // ---- scatter nodes by level: node|childmask and parent node, by position ----
  for (int k = 0; k < 4; ++k) {
    int v2 = tid + k * 1024;
    int pos = atomicAdd(&offs[dep[v2]], 1);
    int c = v2 & 63, r = v2 >> 6;
    unsigned msk = 0;
    if (r > 0  && par[v2 - 64] == v2) msk |= 1;
    if (c > 0  && par[v2 - 1]  == v2) msk |= 2;
    if (c < 63 && par[v2 + 1]  == v2) msk |= 4;
    if (r < 63 && par[v2 + 64] == v2) msk |= 8;
    levn16_g[b * 4096 + pos] = (unsigned short)(v2 | (msk << 12));
    parn16_g[b * 4096 + pos] = (unsigned short)par[v2];
  }
}

// ---------------- single-wave LDS-resident tree scan, transposed coalesced I/O ----------------
// Up-pass in SCATTER form: node adds el*acc into parent via ds_add_f32 (wave-ordered);
// removes the childmask gather (4 loads + fma chain) from the per-level critical path.
__global__ __launch_bounds__(64) void scan_kernel(
    float* __restrict__ buft, const float* __restrict__ ewt,
    const unsigned short* __restrict__ levn16_g,
    const unsigned short* __restrict__ parn16_g,
    const int* __restrict__ levs_g) {
  __shared__ float pr[32776];            // 4 planes x 4097 float2
  __shared__ unsigned int topo[4096];    // levn16 | parn16<<16, by position
  __shared__ unsigned short lvs[4104];
  int bid = blockIdx.x;
  int b = bid >> 6;
  int cg = bid & 63;
  int lane = threadIdx.x;
  int nlev = levs_g[b * LSP + 4098];
  size_t tbase = (size_t)(b * 64 + cg) * 4096;
  float2* pr2 = reinterpret_cast<float2*>(pr);
  // ---- stage (fully coalesced); acc initialized to f ----
  const float4* bt4 = reinterpret_cast<const float4*>(buft) + tbase;
  const float4* et4 = reinterpret_cast<const float4*>(ewt) + tbase;
  for (int n = lane; n < 4096; n += 64) {
    float4 bv = bt4[n];
    float4 ev = et4[n];
    pr2[0 * 4097 + n] = make_float2(bv.x, ev.x);
    pr2[1 * 4097 + n] = make_float2(bv.y, ev.y);
    pr2[2 * 4097 + n] = make_float2(bv.z, ev.z);
    pr2[3 * 4097 + n] = make_float2(bv.w, ev.w);
  }
  const unsigned int* lv32 = reinterpret_cast<const unsigned int*>(levn16_g + b * 4096);
  const unsigned int* pn32 = reinterpret_cast<const unsigned int*>(parn16_g + b * 4096);
  for (int i2 = lane; i2 < 2048; i2 += 64) {
    unsigned int a = lv32[i2], p = pn32[i2];
    topo[2 * i2]     = (a & 0xFFFFu) | (p << 16);
    topo[2 * i2 + 1] = (a >> 16) | (p & 0xFFFF0000u);
  }
  for (int i = lane; i <= nlev; i += 64) lvs[i] = (unsigned short)levs_g[b * LSP + i];
  __syncthreads();
  int ch = lane & 3;
  int slot = lane >> 2;            // 0..15
  int cpl = ch * 4097;             // plane offset in float2
  // ---- up (scatter): levels nlev-1 .. 1, node v adds el*acc[v] into parent ----
  if (nlev > 1) {
    int s = lvs[nlev - 1], e = lvs[nlev];     // deepest level
    int jn = s + slot;
    unsigned int pkn = topo[jn & 4095];
    for (int lev = nlev - 1; lev >= 1; --lev) {
      int ce = e;
      int j = jn;
      unsigned int pk = pkn;
      if (lev > 1) {                           // prefetch next (shallower) level
        e = s; s = lvs[lev - 1];
        jn = s + slot;
        pkn = topo[jn & 4095];
      }
      bool first = true;
      while (j < ce) {
        if (!first) pk = topo[j];
        first = false;
        int v = pk & 4095;
        int p = (pk >> 16) & 4095;
        float2 self = pr2[cpl + v];            // {acc, el}
        atomicAdd(&pr[(cpl + p) * 2], self.y * self.x);
        j += 16;
      }
      __builtin_amdgcn_wave_barrier();         // pin ordering between levels
    }
  }
  __builtin_amdgcn_wave_barrier();
  // ---- down: out[v] = up[v] + w*(out[p] - w*up[v]) ----
  if (nlev > 1) {
    int s = lvs[1], e = lvs[2];
    int jn = s + slot;
    unsigned int pkn = topo[jn & 4095];
    for (int lev = 1; lev < nlev; ++lev) {
      int ce = e;
      int j = jn;
      unsigned int pk = pkn;
      if (lev + 1 < nlev) {
        s = e; e = lvs[lev + 2];
        jn = s + slot;
        pkn = topo[jn & 4095];
      }
      bool first = true;
      while (j < ce) {
        if (!first) pk = topo[j];
        first = false;
        int v = pk & 4095;
        int p = (pk >> 16) & 4095;
        float2 self = pr2[cpl + v];          // {bl, el}
        float pb = pr[(cpl + p) * 2];
        float w = self.y, uv = self.x;
        pr[(cpl + v) * 2] = uv + w * (pb - w * uv);
        j += 16;
      }
      __builtin_amdgcn_wave_barrier();
    }
  }
  __syncthreads();
  // ---- write back (coalesced) ----
  float4* bw4 = reinterpret_cast<float4*>(buft) + tbase;
  for (int n = lane; n < 4096; n += 64) {
    float2 c0 = pr2[0 * 4097 + n];
    float2 c1 = pr2[1 * 4097 + n];
    float2 c2 = pr2[2 * 4097 + n];
    float2 c3 = pr2[3 * 4097 + n];
    bw4[n] = make_float4(c0.x, c1.x, c2.x, c3.x);
  }
}

// ---------------- post-scan: LN(d=256) -> *Cs + ds*xs -> LN -> *z ----------------
// buft is transposed: fo = buft[((b*64 + d/4)*4096 + l)*4 + d%4]
__global__ __launch_bounds__(256) void post_kernel(
    const float* __restrict__ buft, const float* __restrict__ Cs,
    const float* __restrict__ xs, const float* __restrict__ ds,
    const float* __restrict__ hng, const float* __restrict__ hnb,
    const float* __restrict__ ong, const float* __restrict__ onb,
    float* __restrict__ zya) {
  int m = blockIdx.x, d = threadIdx.x;
  int b = m >> 12, l = m & (LB - 1);
  size_t idx = (size_t)m * 256 + d;
  float fo = buft[((size_t)(b * 64 + (d >> 2)) * 4096 + l) * 4 + (d & 3)];
  float mu = block_sum256(fo) * (1.f / 256.f);
  float dv = fo - mu;
  float var = block_sum256(dv * dv) * (1.f / 256.f);
  float ho = dv * (1.0f / sqrtf(var + 1e-5f)) * hng[d] + hnb[d];
  float y = ho * Cs[m] + ds[d] * xs[idx];
  float mu2 = block_sum256(y) * (1.f / 256.f);
  float dy = y - mu2;
  float var2 = block_sum256(dy * dy) * (1.f / 256.f);
  float y2 = dy * (1.0f / sqrtf(var2 + 1e-5f)) * ong[d] + onb[d];
  zya[idx] = y2 * zya[idx];     // ya = y * z (in place over z)
}

// ---------------- launcher ----------------
extern "C" void kernel_launch(void* const* d_in, const int* in_sizes, int n_in,
                              void* d_out, int out_size, void* d_ws, size_t ws_size,
                              hipStream_t stream) {
  (void)in_sizes; (void)n_in; (void)out_size; (void)ws_size;
  const float* x      = (const float*)d_in[0];
  const float* ln1g   = (const float*)d_in[1];
  const float* ln1b   = (const float*)d_in[2];
  const float* ln2g   = (const float*)d_in[3];
  const float* ln2b   = (const float*)d_in[4];
  const float* w_in   = (const float*)d_in[5];
  const float* conv_w = (const float*)d_in[6];
  const float* xw     = (const float*)d_in[7];
  const float* dtw    = (const float*)d_in[8];
  const float* dtb    = (const float*)d_in[9];
  const float* alogs  = (const float*)d_in[10];
  const float* dsv    = (const float*)d_in[11];
  const float* hng    = (const float*)d_in[12];
  const float* hnb    = (const float*)d_in[13];
  const float* ong    = (const float*)d_in[14];
  const float* onb    = (const float*)d_in[15];
  const float* w_out  = (const float*)d_in[16];
  const float* mw1    = (const float*)d_in[17];
  const float* mb1    = (const float*)d_in[18];
  const float* mw2    = (const float*)d_in[19];
  const float* mb2    = (const float*)d_in[20];

  char* ws = (char*)d_ws;
  float* h    = (float*)(ws + 0);            // 16MB (h, later x1)
  float* z    = (float*)(ws + 16777216);     // 33.5MB (z, later ya in-place)
  float* xcp  = (float*)(ws + 50331648);     // 33.5MB (xc_pre, later h2)
  float* xs   = (float*)(ws + 83886080);     // 33.5MB
  float* dAt  = (float*)(ws + 117440512);    // 33.5MB transposed deltaA
  float* featt= (float*)(ws + 150994944);    // 33.5MB transposed feat -> scan buf
  float* Cs   = (float*)(ws + 184549376);
  float* ssq  = (float*)(ws + 184680448);
  float* wr   = (float*)(ws + 184811520);
  float* wd   = (float*)(ws + 184942592);
  unsigned short* levn16 = (unsigned short*)(ws + 185073664);   // 64KB
  unsigned short* parn16 = (unsigned short*)(ws + 185204736);   // 64KB
  int*   levs = (int*)(ws + 185335808);
  float* midg = xs;      // 67MB spans xs+dAt (both dead by then)
  float* x1   = h;
  float* h2   = xcp;

  ln128_kernel<<<MROWS / 4, 256, 0, stream>>>(x, ln1g, ln1b, h, 1e-6f);
  gemm_kernel<1><<<dim3(8, 512), 256, 0, stream>>>(h, w_in, xcp, z, nullptr, nullptr,
                                                   MROWS, 512, 128);
  convfeat_kernel<<<MROWS, 256, 0, stream>>>(xcp, conv_w, xw, dtw, dtb, alogs,
                                             xs, dAt, featt, Cs, ssq);
  gridw_kernel<<<MROWS, 256, 0, stream>>>(xs, ssq, wr, wd);
  mst_kernel<<<NB, 1024, 0, stream>>>(wr, wd, levn16, parn16, levs);
  scan_kernel<<<512, 64, 0, stream>>>(featt, dAt, levn16, parn16, levs);
  post_kernel<<<MROWS, 256, 0, stream>>>(featt, Cs, xs, dsv, hng, hnb, ong, onb, z);
  gemm_kernel<2><<<dim3(2, 512), 256, 0, stream>>>(z, w_out, x1, nullptr, nullptr, x,
                                                   MROWS, 128, 256);
  ln128_kernel<<<MROWS / 4, 256, 0, stream>>>(x1, ln2g, ln2b, h2, 1e-6f);
  gemm_kernel<3><<<dim3(8, 512), 256, 0, stream>>>(h2, mw1, midg, nullptr, mb1, nullptr,
                                                   MROWS, 512, 128);
  gemm_kernel<4><<<dim3(2, 512), 256, 0, stream>>>(midg, mw2, (float*)d_out, nullptr,
                                                   mb2, x1, MROWS, 128, 512);
}

// Round 13
// 840.999 us; speedup vs baseline: 1.2279x; 1.0397x over previous
//
#include <hip/hip_runtime.h>
#include <hip/hip_bf16.h>
#include <cstdint>

#define BIGF 1e30f
constexpr int LB   = 4096;           // L = H*W
constexpr int NB   = 8;              // batch
constexpr int MROWS = NB * LB;       // 32768 pixel rows
constexpr int LSP  = 4104;           // level-start stride per batch

// ---------------- helpers ----------------
__device__ __forceinline__ float warp_sum(float v) {
#pragma unroll
  for (int off = 32; off; off >>= 1) v += __shfl_xor(v, off);
  return v;
}

__device__ __forceinline__ float block_sum256(float v) {
  __shared__ float sm[4];
  v = warp_sum(v);
  __syncthreads();
  if ((threadIdx.x & 63) == 0) sm[threadIdx.x >> 6] = v;
  __syncthreads();
  return sm[0] + sm[1] + sm[2] + sm[3];
}

// ---------------- LayerNorm over last dim 128 ----------------
__global__ __launch_bounds__(256) void ln128_kernel(
    const float* __restrict__ X, const float* __restrict__ g,
    const float* __restrict__ bb, float* __restrict__ O, float eps) {
  int wave = threadIdx.x >> 6, lane = threadIdx.x & 63;
  int row = blockIdx.x * 4 + wave;
  const float* xr = X + (size_t)row * 128;
  float x0 = xr[lane], x1 = xr[lane + 64];
  float mu = warp_sum(x0 + x1) * (1.0f / 128.0f);
  float d0 = x0 - mu, d1 = x1 - mu;
  float var = warp_sum(d0 * d0 + d1 * d1) * (1.0f / 128.0f);
  float s = 1.0f / sqrtf(var + eps);
  float* orow = O + (size_t)row * 128;
  orow[lane]      = d0 * s * g[lane]      + bb[lane];
  orow[lane + 64] = d1 * s * g[lane + 64] + bb[lane + 64];
}

// ---------------- f32 GEMM 64x64 tile (EPI 2: +addsrc, EPI 4: +bias+addsrc) ----------------
template<int EPI>
__global__ __launch_bounds__(256) void gemm_kernel(
    const float* __restrict__ A, const float* __restrict__ W,
    float* __restrict__ C, float* __restrict__ C2,
    const float* __restrict__ bias, const float* __restrict__ addsrc,
    int M, int N, int K) {
  __shared__ float As[32][68];
  __shared__ float Bs[32][68];
  int t = threadIdx.x;
  int tx = t & 15, ty = t >> 4;
  int bm = blockIdx.y * 64, bn = blockIdx.x * 64;
  float acc[4][4] = {};
  for (int k0 = 0; k0 < K; k0 += 32) {
#pragma unroll
    for (int hh = 0; hh < 2; ++hh) {
      int q = t + hh * 256;
      int r = q >> 3, kc = q & 7;
      float4 a4 = reinterpret_cast<const float4*>(A + (size_t)(bm + r) * K + k0)[kc];
      float4 b4 = reinterpret_cast<const float4*>(W + (size_t)(bn + r) * K + k0)[kc];
      As[kc * 4 + 0][r] = a4.x; As[kc * 4 + 1][r] = a4.y;
      As[kc * 4 + 2][r] = a4.z; As[kc * 4 + 3][r] = a4.w;
      Bs[kc * 4 + 0][r] = b4.x; Bs[kc * 4 + 1][r] = b4.y;
      Bs[kc * 4 + 2][r] = b4.z; Bs[kc * 4 + 3][r] = b4.w;
    }
    __syncthreads();
#pragma unroll
    for (int kk = 0; kk < 32; ++kk) {
      float4 av = *reinterpret_cast<const float4*>(&As[kk][ty * 4]);
      float4 bv = *reinterpret_cast<const float4*>(&Bs[kk][tx * 4]);
      float aa[4] = {av.x, av.y, av.z, av.w};
      float bbv[4] = {bv.x, bv.y, bv.z, bv.w};
#pragma unroll
      for (int i = 0; i < 4; ++i)
#pragma unroll
        for (int j = 0; j < 4; ++j) acc[i][j] += aa[i] * bbv[j];
    }
    __syncthreads();
  }
#pragma unroll
  for (int i = 0; i < 4; ++i) {
    int m = bm + ty * 4 + i;
#pragma unroll
    for (int j = 0; j < 4; ++j) {
      int n = bn + tx * 4 + j;
      float v = acc[i][j];
      if (EPI == 2) {
        C[(size_t)m * N + n] = v + addsrc[(size_t)m * N + n];
      } else if (EPI == 4) {
        C[(size_t)m * N + n] = v + bias[n] + addsrc[(size_t)m * N + n];
      }
    }
  }
}

// ---------------- f32 GEMM 128x128 tile (EPI 1: split+silu, EPI 3: +bias+gelu) ----------------
template<int EPI>
__global__ __launch_bounds__(256) void gemm128_kernel(
    const float* __restrict__ A, const float* __restrict__ W,
    float* __restrict__ C, float* __restrict__ C2,
    const float* __restrict__ bias, int M, int N, int K) {
  __shared__ float As[32][132];
  __shared__ float Bs[32][132];
  int t = threadIdx.x;
  int tx = t & 15, ty = t >> 4;
  int bm = blockIdx.y * 128, bn = blockIdx.x * 128;
  float acc[8][8] = {};
  for (int k0 = 0; k0 < K; k0 += 32) {
#pragma unroll
    for (int hh = 0; hh < 4; ++hh) {
      int q = t + hh * 256;
      int r = q >> 3, kc = q & 7;
      float4 a4 = *reinterpret_cast<const float4*>(A + (size_t)(bm + r) * K + k0 + kc * 4);
      float4 b4 = *reinterpret_cast<const float4*>(W + (size_t)(bn + r) * K + k0 + kc * 4);
      As[kc * 4 + 0][r] = a4.x; As[kc * 4 + 1][r] = a4.y;
      As[kc * 4 + 2][r] = a4.z; As[kc * 4 + 3][r] = a4.w;
      Bs[kc * 4 + 0][r] = b4.x; Bs[kc * 4 + 1][r] = b4.y;
      Bs[kc * 4 + 2][r] = b4.z; Bs[kc * 4 + 3][r] = b4.w;
    }
    __syncthreads();
#pragma unroll
    for (int kk = 0; kk < 32; ++kk) {
      float4 a0 = *reinterpret_cast<const float4*>(&As[kk][ty * 4]);
      float4 a1 = *reinterpret_cast<const float4*>(&As[kk][64 + ty * 4]);
      float4 b0 = *reinterpret_cast<const float4*>(&Bs[kk][tx * 4]);
      float4 b1 = *reinterpret_cast<const float4*>(&Bs[kk][64 + tx * 4]);
      float aa[8] = {a0.x, a0.y, a0.z, a0.w, a1.x, a1.y, a1.z, a1.w};
      float bb2[8] = {b0.x, b0.y, b0.z, b0.w, b1.x, b1.y, b1.z, b1.w};
#pragma unroll
      for (int i = 0; i < 8; ++i)
#pragma unroll
        for (int j = 0; j < 8; ++j) acc[i][j] += aa[i] * bb2[j];
    }
    __syncthreads();
  }
#pragma unroll
  for (int i = 0; i < 8; ++i) {
    int m = bm + (i >> 2) * 64 + ty * 4 + (i & 3);
#pragma unroll
    for (int j = 0; j < 8; ++j) {
      int n = bn + (j >> 2) * 64 + tx * 4 + (j & 3);
      float v = acc[i][j];
      if (EPI == 1) {
        if (n < 256) C[(size_t)m * 256 + n] = v;
        else C2[(size_t)m * 256 + (n - 256)] = v / (1.0f + __expf(-v));
      } else if (EPI == 3) {
        float u = v + bias[n];
        float xg = 1.5957691216057308f * (u + 0.044715f * u * u * u);
        C[(size_t)m * N + n] = u / (1.0f + __expf(-xg));   // 0.5u(1+tanh(.)) = u*sigmoid(2.)
      }
    }
  }
}

// ---------------- depthwise conv3x3 + silu + x_dbl/dts/deltaA/feat ----------------
// feat/dA written TRANSPOSED: [b][group=d>>2][node][d&3]
__global__ __launch_bounds__(256) void convfeat_kernel(
    const float* __restrict__ xcpre, const float* __restrict__ cw,
    const float* __restrict__ xw, const float* __restrict__ dtw,
    const float* __restrict__ dtb, const float* __restrict__ alogs,
    float* __restrict__ xs, float* __restrict__ dAt, float* __restrict__ featt,
    float* __restrict__ Cs, float* __restrict__ ssq) {
  int m = blockIdx.x;
  int d = threadIdx.x;
  int l = m & (LB - 1), b = m >> 12;
  int r = l >> 6, c = l & 63;
  float acc = 0.f;
#pragma unroll
  for (int ky = 0; ky < 3; ++ky) {
    int rr = r + ky - 1;
    if (rr < 0 || rr > 63) continue;
#pragma unroll
    for (int kx = 0; kx < 3; ++kx) {
      int cc = c + kx - 1;
      if (cc < 0 || cc > 63) continue;
      int ml = (b << 12) + (rr << 6) + cc;
      acc += xcpre[(size_t)ml * 256 + d] * cw[d * 9 + ky * 3 + kx];
    }
  }
  float xv = acc / (1.0f + __expf(-acc));        // silu
  xs[(size_t)m * 256 + d] = xv;
  float p[11];
#pragma unroll
  for (int i = 0; i < 10; ++i) p[i] = xv * xw[i * 256 + d];
  p[10] = xv * xv;
  __shared__ float sm[4][11];
#pragma unroll
  for (int i = 0; i < 11; ++i) p[i] = warp_sum(p[i]);
  int wv = d >> 6;
  if ((d & 63) == 0) {
    for (int i = 0; i < 11; ++i) sm[wv][i] = p[i];
  }
  __syncthreads();
  float red[11];
#pragma unroll
  for (int i = 0; i < 11; ++i) red[i] = sm[0][i] + sm[1][i] + sm[2][i] + sm[3][i];
  float xdt = dtb[d];
#pragma unroll
  for (int rr2 = 0; rr2 < 8; ++rr2) xdt += red[rr2] * dtw[d * 8 + rr2];
  float sp = fmaxf(xdt, 0.f) + __logf(1.0f + __expf(-fabsf(xdt)));   // softplus
  float As_ = -__expf(alogs[d]);
  size_t tidx = ((size_t)(b * 64 + (d >> 2)) * 4096 + l) * 4 + (d & 3);
  dAt[tidx]   = __expf(sp * As_);
  featt[tidx] = sp * red[8] * xv;
  if (d == 0) { Cs[m] = red[9]; ssq[m] = red[10]; }
}

// ---------------- grid edge weights wr/wd (exact expf — MST weights must match ref tree) ----
__global__ __launch_bounds__(256) void gridw_kernel(
    const float* __restrict__ xs, const float* __restrict__ ssq,
    float* __restrict__ wrg, float* __restrict__ wdg) {
  int m = blockIdx.x, d = threadIdx.x;
  int l = m & (LB - 1);
  int r = l >> 6, c = l & 63;
  float a = xs[(size_t)m * 256 + d];
  float br = (c < 63) ? xs[(size_t)(m + 1) * 256 + d] : 0.f;
  float bd = (r < 63) ? xs[(size_t)(m + 64) * 256 + d] : 0.f;
  float s1 = warp_sum(a * br);
  float s2 = warp_sum(a * bd);
  __shared__ float sm[4][2];
  int wv = d >> 6;
  if ((d & 63) == 0) { sm[wv][0] = s1; sm[wv][1] = s2; }
  __syncthreads();
  if (d == 0) {
    float dotr = sm[0][0] + sm[1][0] + sm[2][0] + sm[3][0];
    float dotd = sm[0][1] + sm[1][1] + sm[2][1] + sm[3][1];
    float na = sqrtf(ssq[m]);
    float wrv = BIGF, wdv = BIGF;
    if (c < 63) { float den = fmaxf(na * sqrtf(ssq[m + 1]), 1e-8f);  wrv = expf(-(dotr / den)); }
    if (r < 63) { float den = fmaxf(na * sqrtf(ssq[m + 64]), 1e-8f); wdv = expf(-(dotd / den)); }
    wrg[m] = wrv; wdg[m] = wdv;
  }
}

// ---------------- Boruvka MST + Euler-tour rooting (O(log V)) + levels ----------------
// Output: topo32[pos] = node | childmask<<12 | par<<16 ; levs_g per batch.
// Directions: 0=N(-64), 1=W(-1), 2=E(+1), 3=S(+64); rev(d)=3-d.
__global__ __launch_bounds__(1024) void mst_kernel(
    const float* __restrict__ wr_g, const float* __restrict__ wd_g,
    unsigned int* __restrict__ topo_g, int* __restrict__ levs_g) {
  __shared__ int pool[24592];          // 98.4 KB, phase-overlaid
  __shared__ unsigned char flagR[4096];
  __shared__ unsigned char flagD[4096];
  __shared__ int ncomp_s;
  __shared__ int wred[16];
  int b = blockIdx.x, tid = threadIdx.x;
  // ---- phase A layout (Boruvka) ----
  float* wrs = (float*)pool;
  float* wds = (float*)(pool + 4096);
  int* comp = pool + 8192;
  int* lnk  = pool + 12288;
  unsigned int* bestw = (unsigned int*)(pool + 16384);
  int* beste = pool + 20480;
  const float* wrb = wr_g + b * 4096;
  const float* wdb = wd_g + b * 4096;
  for (int k = 0; k < 4; ++k) {
    int i = tid + k * 1024;
    wrs[i] = wrb[i]; wds[i] = wdb[i];
    comp[i] = i; flagR[i] = 0; flagD[i] = 0;
  }
  __syncthreads();
  for (int phase = 0; phase < 13; ++phase) {
    for (int k = 0; k < 4; ++k) {
      int c = tid + k * 1024;
      bestw[c] = 0xFFFFFFFFu; beste[c] = 0x7FFFFFFF; lnk[c] = c;
    }
    if (tid == 0) ncomp_s = 0;
    __syncthreads();
    for (int k = 0; k < 8; ++k) {
      int e = tid + k * 1024;
      int v = e & 4095;
      bool isR = e < 4096;
      int c = v & 63, r = v >> 6;
      bool valid = isR ? (c < 63) : (r < 63);
      if (valid) {
        int u = isR ? v + 1 : v + 64;
        int ca = comp[v], cb = comp[u];
        if (ca != cb) {
          unsigned wbits = __float_as_uint(isR ? wrs[v] : wds[v]);
          atomicMin(&bestw[ca], wbits);
          atomicMin(&bestw[cb], wbits);
        }
      }
    }
    __syncthreads();
    for (int k = 0; k < 8; ++k) {
      int e = tid + k * 1024;
      int v = e & 4095;
      bool isR = e < 4096;
      int c = v & 63, r = v >> 6;
      bool valid = isR ? (c < 63) : (r < 63);
      if (valid) {
        int u = isR ? v + 1 : v + 64;
        int ca = comp[v], cb = comp[u];
        if (ca != cb) {
          unsigned wbits = __float_as_uint(isR ? wrs[v] : wds[v]);
          if (wbits == bestw[ca]) atomicMin(&beste[ca], e);
          if (wbits == bestw[cb]) atomicMin(&beste[cb], e);
        }
      }
    }
    __syncthreads();
    for (int k = 0; k < 4; ++k) {
      int cc = tid + k * 1024;
      int e = beste[cc];
      if (e != 0x7FFFFFFF) {
        int v = e & 4095;
        bool isR = e < 4096;
        int u = isR ? v + 1 : v + 64;
        if (isR) flagR[v] = 1; else flagD[v] = 1;
        int ca = comp[v], cb = comp[u];
        lnk[cc] = (ca == cc) ? cb : ca;
      }
    }
    __syncthreads();
    for (int k = 0; k < 4; ++k) {
      int cc = tid + k * 1024;
      int l = lnk[cc];
      if (l != cc && lnk[l] == cc && cc < l) lnk[cc] = cc;
    }
    __syncthreads();
    for (int it = 0; it < 12; ++it) {
      for (int k = 0; k < 4; ++k) {
        int cc = tid + k * 1024;
        lnk[cc] = lnk[lnk[cc]];
      }
      __syncthreads();
    }
    for (int k = 0; k < 4; ++k) {
      int i = tid + k * 1024;
      comp[i] = lnk[comp[i]];
      if (comp[i] == i) atomicAdd(&ncomp_s, 1);
    }
    __syncthreads();
    if (ncomp_s <= 1) break;
    __syncthreads();
  }
  // ---- phase B layout (Euler tour; overlays dead Boruvka arrays) ----
  unsigned short* nxt = (unsigned short*)pool;        // [16400]
  short*          dsv = (short*)(pool + 8200);        // [16400]
  int* par = pool + 16400;                            // [4096]
  int* dep = pool + 20496;                            // [4096]
  const int NIL = 16384;
  unsigned short rn[16];
  int rd[16];
  int validm = 0;
  for (int k = 0; k < 4; ++k) { int i = tid + k * 1024; par[i] = 0; dep[i] = 0; }
#pragma unroll
  for (int k = 0; k < 16; ++k) {
    int a = tid + k * 1024;
    int u = a >> 2, d = a & 3;
    int c = u & 63, r = u >> 6;
    int mu = 0;
    if (r > 0  && flagD[u - 64]) mu |= 1;
    if (c > 0  && flagR[u - 1])  mu |= 2;
    if (c < 63 && flagR[u])      mu |= 4;
    if (r < 63 && flagD[u])      mu |= 8;
    unsigned short nx = NIL; short dv = 0;
    if (mu & (1 << d)) {
      validm |= 1 << k;
      int v = u + ((d == 0) ? -64 : (d == 1) ? -1 : (d == 2) ? 1 : 64);
      int cv = v & 63, rv = v >> 6;
      int mv = 0;
      if (rv > 0  && flagD[v - 64]) mv |= 1;
      if (cv > 0  && flagR[v - 1])  mv |= 2;
      if (cv < 63 && flagR[v])      mv |= 4;
      if (rv < 63 && flagD[v])      mv |= 8;
      int din = 3 - d;
      int hi = mv >> (din + 1);
      int dn = hi ? (din + __ffs(hi)) : (__ffs(mv) - 1);
      int nxv = v * 4 + dn;
      int m0 = (flagR[0] ? 4 : 0) | (flagD[0] ? 8 : 0);
      int a0 = __ffs(m0) - 1;                 // start arc (root node 0)
      if (v == 0 && nxv == a0) nxv = NIL;     // break circuit before start
      nx = (unsigned short)nxv;
      dv = 1;
    }
    nxt[a] = nx; dsv[a] = dv;
    rn[k] = nx; rd[k] = dv;
  }
  if (tid == 0) { nxt[NIL] = NIL; dsv[NIL] = 0; }
  __syncthreads();
#pragma unroll 1
  for (int it = 0; it < 13; ++it) {
    unsigned short nn[16]; short nd[16];
#pragma unroll
    for (int k = 0; k < 16; ++k) { nn[k] = nxt[rn[k]]; nd[k] = dsv[rn[k]]; }
    __syncthreads();
#pragma unroll
    for (int k = 0; k < 16; ++k) {
      int a = tid + k * 1024;
      rd[k] += nd[k];
      rn[k] = nn[k];
      nxt[a] = rn[k]; dsv[a] = (short)rd[k];
    }
    __syncthreads();
  }
#pragma unroll
  for (int k = 0; k < 16; ++k) if (validm & (1 << k)) {
    int a = tid + k * 1024;
    int u = a >> 2, d = a & 3;
    int v = u + ((d == 0) ? -64 : (d == 1) ? -1 : (d == 2) ? 1 : 64);
    int rb = v * 4 + (3 - d);
    if (rd[k] > (int)dsv[rb]) par[v] = u;
  }
  __syncthreads();
#pragma unroll
  for (int k = 0; k < 16; ++k) {
    int a = tid + k * 1024;
    int u = a >> 2, d = a & 3;
    unsigned short nx = NIL; short dv = 0;
    if (validm & (1 << k)) {
      int v = u + ((d == 0) ? -64 : (d == 1) ? -1 : (d == 2) ? 1 : 64);
      int cv = v & 63, rv = v >> 6;
      int mv = 0;
      if (rv > 0  && flagD[v - 64]) mv |= 1;
      if (cv > 0  && flagR[v - 1])  mv |= 2;
      if (cv < 63 && flagR[v])      mv |= 4;
      if (rv < 63 && flagD[v])      mv |= 8;
      int din = 3 - d;
      int hi = mv >> (din + 1);
      int dn = hi ? (din + __ffs(hi)) : (__ffs(mv) - 1);
      int nxv = v * 4 + dn;
      int m0 = (flagR[0] ? 4 : 0) | (flagD[0] ? 8 : 0);
      int a0 = __ffs(m0) - 1;
      if (v == 0 && nxv == a0) nxv = NIL;
      nx = (unsigned short)nxv;
      dv = (par[v] == u) ? (short)1 : (short)-1;
    }
    nxt[a] = nx; dsv[a] = dv;
    rn[k] = nx; rd[k] = dv;
  }
  __syncthreads();
#pragma unroll 1
  for (int it = 0; it < 13; ++it) {
    unsigned short nn[16]; short nd[16];
#pragma unroll
    for (int k = 0; k < 16; ++k) { nn[k] = nxt[rn[k]]; nd[k] = dsv[rn[k]]; }
    __syncthreads();
#pragma unroll
    for (int k = 0; k < 16; ++k) {
      int a = tid + k * 1024;
      rd[k] += nd[k];
      rn[k] = nn[k];
      nxt[a] = rn[k]; dsv[a] = (short)rd[k];
    }
    __syncthreads();
  }
#pragma unroll
  for (int k = 0; k < 16; ++k) if (validm & (1 << k)) {
    int a = tid + k * 1024;
    int u = a >> 2, d = a & 3;
    int v = u + ((d == 0) ? -64 : (d == 1) ? -1 : (d == 2) ? 1 : 64);
    if (par[v] == u) dep[v] = 1 - rd[k];
  }
  __syncthreads();
  // ---- max depth ----
  int md = 0;
  for (int k = 0; k < 4; ++k) md = max(md, dep[tid + k * 1024]);
#pragma unroll
  for (int off = 32; off; off >>= 1) md = max(md, __shfl_xor(md, off));
  if ((tid & 63) == 0) wred[tid >> 6] = md;
  __syncthreads();
  if (tid == 0) {
    int m = 0;
    for (int i = 0; i < 16; ++i) m = max(m, wred[i]);
    wred[0] = m;
  }
  __syncthreads();
  int maxd = wred[0];
  __syncthreads();
  // ---- histogram + exclusive prefix over depth buckets ----
  int* cnt  = pool;
  int* offs = pool + 4096;
  for (int k = 0; k < 4; ++k) cnt[tid + k * 1024] = 0;
  __syncthreads();
  for (int k = 0; k < 4; ++k) atomicAdd(&cnt[dep[tid + k * 1024]], 1);
  __syncthreads();
  int base4 = tid * 4;
  int c0 = cnt[base4], c1 = cnt[base4 + 1], c2 = cnt[base4 + 2], c3 = cnt[base4 + 3];
  int tsum = c0 + c1 + c2 + c3;
  int lane = tid & 63, wid = tid >> 6;
  int iv = tsum;
  for (int off = 1; off < 64; off <<= 1) {
    int n = __shfl_up(iv, off);
    if (lane >= off) iv += n;
  }
  if (lane == 63) wred[wid] = iv;
  __syncthreads();
  if (tid == 0) {
    int acc = 0;
    for (int i = 0; i < 16; ++i) { int t = wred[i]; wred[i] = acc; acc += t; }
  }
  __syncthreads();
  int excl = iv - tsum + wred[wid];
  offs[base4]     = excl;
  offs[base4 + 1] = excl + c0;
  offs[base4 + 2] = excl + c0 + c1;
  offs[base4 + 3] = excl + c0 + c1 + c2;
  __syncthreads();
  for (int idx = tid; idx <= maxd; idx += 1024) levs_g[b * LSP + idx] = offs[idx];
  if (tid == 0) {
    levs_g[b * LSP + maxd + 1] = 4096;
    levs_g[b * LSP + 4098] = maxd + 1;
  }
  __syncthreads();   // levs_g copy must finish reading offs before scatter mutates it
  // ---- scatter: topo32[pos] = node | childmask<<12 | par<<16 ----
  for (int k = 0; k < 4; ++k) {
    int v2 = tid + k * 1024;
    int pos = atomicAdd(&offs[dep[v2]], 1);
    int c = v2 & 63, r = v2 >> 6;
    unsigned msk = 0;
    if (r > 0  && par[v2 - 64] == v2) msk |= 1;
    if (c > 0  && par[v2 - 1]  == v2) msk |= 2;
    if (c < 63 && par[v2 + 1]  == v2) msk |= 4;
    if (r < 63 && par[v2 + 64] == v2) msk |= 8;
    topo_g[b * 4096 + pos] =
        (unsigned)v2 | (msk << 12) | ((unsigned)par[v2] << 16);
  }
}

// ---------------- scan v3: 72KB LDS (acc+lvs), topo/el from global, software-pipelined ----------------
// 512 blocks x 64 threads, 2 blocks/CU -> all resident -> single scheduling round.
__global__ __launch_bounds__(64) void scan_kernel(
    float* __restrict__ buft, const float* __restrict__ ewt,
    const unsigned int* __restrict__ topo_g, const int* __restrict__ levs_g) {
  __shared__ float acc[16384];           // [node*4 + ch], 64 KB
  __shared__ unsigned short lvs[4104];   // 8 KB
  int bid = blockIdx.x;
  int b = bid >> 6, cg = bid & 63;
  int lane = threadIdx.x;
  int ch = lane & 3, slot = lane >> 2;
  int nlev = levs_g[b * LSP + 4098];
  size_t fbase = (size_t)(b * 64 + cg) * 16384;
  const float4* bt4 = reinterpret_cast<const float4*>(buft + fbase);
  const float*  ewf = ewt + fbase;
  const float4* et4 = reinterpret_cast<const float4*>(ewf);
  const unsigned int* tp = topo_g + b * 4096;
  // ---- stage acc=f (coalesced); warm ew slab into L2 ----
  float4* acc4 = reinterpret_cast<float4*>(acc);
  float wsum = 0.f;
  for (int n = lane; n < 4096; n += 64) {
    acc4[n] = bt4[n];
    float4 ev = et4[n];
    wsum += ev.x + ev.y + ev.z + ev.w;
  }
  asm volatile("" :: "v"(wsum));         // keep warming reads live
  for (int i = lane; i <= nlev; i += 64) lvs[i] = (unsigned short)levs_g[b * LSP + i];
  __syncthreads();
  // ======== UP: levels nlev-1 .. 1 (scatter child -> parent) ========
  if (nlev > 1) {
    // prologue: A = level nlev-1, B = level nlev-2
    int sA = lvs[nlev - 1], eA = lvs[nlev];
    int jA = sA + slot;
    unsigned tAv = tp[jA < 4096 ? jA : 4095];
    int vA = tAv & 4095, pA = (tAv >> 16) & 4095;
    float elA = ewf[vA * 4 + ch];
    int sB = 0, eB = 0, jB = 0; unsigned tBv = 0;
    if (nlev - 2 >= 1) { sB = lvs[nlev - 2]; eB = sA; jB = sB + slot; tBv = tp[jB < 4096 ? jB : 4095]; }
    for (int lev = nlev - 1; lev >= 1; --lev) {
      // decode B, issue el(B); issue topo(C)
      int vB = tBv & 4095, pB = (tBv >> 16) & 4095;
      float elB = 0.f;
      if (lev - 1 >= 1) elB = ewf[vB * 4 + ch];
      int sC = 0, jC = 0; unsigned tCv = 0;
      if (lev - 2 >= 1) { sC = lvs[lev - 2]; jC = sC + slot; tCv = tp[jC < 4096 ? jC : 4095]; }
      // process level A
      if (jA < eA) {
        float a = acc[vA * 4 + ch];
        atomicAdd(&acc[pA * 4 + ch], elA * a);
        for (int j = jA + 16; j < eA; j += 16) {       // big levels (rare)
          unsigned t = tp[j];
          int v = t & 4095, p = (t >> 16) & 4095;
          float e = ewf[v * 4 + ch];
          float av = acc[v * 4 + ch];
          atomicAdd(&acc[p * 4 + ch], e * av);
        }
      }
      __builtin_amdgcn_wave_barrier();
      // rotate A<-B, B<-C
      int oldsB = sB;
      vA = vB; pA = pB; elA = elB; jA = jB; eA = eB; sA = oldsB;
      sB = sC; eB = oldsB; jB = jC; tBv = tCv;
    }
  }
  __builtin_amdgcn_wave_barrier();
  // ======== DOWN: levels 1 .. nlev-1 ========
  if (nlev > 1) {
    // prologue: A = level 1, B = level 2
    int sA = lvs[1], eA = lvs[2];
    int jA = sA + slot;
    unsigned tAv = tp[jA < 4096 ? jA : 4095];
    int vA = tAv & 4095, pA = (tAv >> 16) & 4095;
    float elA = ewf[vA * 4 + ch];
    float uvA = acc[vA * 4 + ch];
    int sB = 0, eB = 0, jB = 0; unsigned tBv = 0;
    if (nlev > 2) { sB = eA; eB = lvs[3 <= nlev ? 3 : nlev]; jB = sB + slot; tBv = tp[jB < 4096 ? jB : 4095]; }
    for (int lev = 1; lev < nlev; ++lev) {
      // decode B, issue el(B) + uv(B); issue topo(C)
      int vB = tBv & 4095, pB = (tBv >> 16) & 4095;
      float elB = 0.f, uvB = 0.f;
      if (lev + 1 < nlev) {
        elB = ewf[vB * 4 + ch];
        uvB = acc[vB * 4 + ch];     // level lev+1 nodes: disjoint from level lev writes
      }
      int sC = 0, eC = 0, jC = 0; unsigned tCv = 0;
      if (lev + 2 < nlev) {
        sC = lvs[lev + 2]; eC = lvs[lev + 3];
        jC = sC + slot; tCv = tp[jC < 4096 ? jC : 4095];
      }
      // process level A
      if (jA < eA) {
        float pb = acc[pA * 4 + ch];
        acc[vA * 4 + ch] = uvA + elA * (pb - elA * uvA);
        for (int j = jA + 16; j < eA; j += 16) {       // big levels (rare)
          unsigned t = tp[j];
          int v = t & 4095, p = (t >> 16) & 4095;
          float e = ewf[v * 4 + ch];
          float uv = acc[v * 4 + ch];
          float pbv = acc[p * 4 + ch];
          acc[v * 4 + ch] = uv + e * (pbv - e * uv);
        }
      }
      __builtin_amdgcn_wave_barrier();
      // rotate A<-B, B<-C
      vA = vB; pA = pB; elA = elB; uvA = uvB; jA = jB; sA = sB; eA = eB;
      sB = sC; eB = eC; jB = jC; tBv = tCv;
    }
  }
  __syncthreads();
  // ---- write back (coalesced) ----
  float4* bw4 = reinterpret_cast<float4*>(buft + fbase);
  for (int n = lane; n < 4096; n += 64) bw4[n] = acc4[n];
}

// ---------------- post-scan: LN(d=256) -> *Cs + ds*xs -> LN -> *z ----------------
__global__ __launch_bounds__(256) void post_kernel(
    const float* __restrict__ buft, const float* __restrict__ Cs,
    const float* __restrict__ xs, const float* __restrict__ ds,
    const float* __restrict__ hng, const float* __restrict__ hnb,
    const float* __restrict__ ong, const float* __restrict__ onb,
    float* __restrict__ zya) {
  int m = blockIdx.x, d = threadIdx.x;
  int b = m >> 12, l = m & (LB - 1);
  size_t idx = (size_t)m * 256 + d;
  float fo = buft[((size_t)(b * 64 + (d >> 2)) * 4096 + l) * 4 + (d & 3)];
  float mu = block_sum256(fo) * (1.f / 256.f);
  float dv = fo - mu;
  float var = block_sum256(dv * dv) * (1.f / 256.f);
  float ho = dv * (1.0f / sqrtf(var + 1e-5f)) * hng[d] + hnb[d];
  float y = ho * Cs[m] + ds[d] * xs[idx];
  float mu2 = block_sum256(y) * (1.f / 256.f);
  float dy = y - mu2;
  float var2 = block_sum256(dy * dy) * (1.f / 256.f);
  float y2 = dy * (1.0f / sqrtf(var2 + 1e-5f)) * ong[d] + onb[d];
  zya[idx] = y2 * zya[idx];     // ya = y * z (in place over z)
}

// ---------------- launcher ----------------
extern "C" void kernel_launch(void* const* d_in, const int* in_sizes, int n_in,
                              void* d_out, int out_size, void* d_ws, size_t ws_size,
                              hipStream_t stream) {
  (void)in_sizes; (void)n_in; (void)out_size; (void)ws_size;
  const float* x      = (const float*)d_in[0];
  const float* ln1g   = (const float*)d_in[1];
  const float* ln1b   = (const float*)d_in[2];
  const float* ln2g   = (const float*)d_in[3];
  const float* ln2b   = (const float*)d_in[4];
  const float* w_in   = (const float*)d_in[5];
  const float* conv_w = (const float*)d_in[6];
  const float* xw     = (const float*)d_in[7];
  const float* dtw    = (const float*)d_in[8];
  const float* dtb    = (const float*)d_in[9];
  const float* alogs  = (const float*)d_in[10];
  const float* dsv    = (const float*)d_in[11];
  const float* hng    = (const float*)d_in[12];
  const float* hnb    = (const float*)d_in[13];
  const float* ong    = (const float*)d_in[14];
  const float* onb    = (const float*)d_in[15];
  const float* w_out  = (const float*)d_in[16];
  const float* mw1    = (const float*)d_in[17];
  const float* mb1    = (const float*)d_in[18];
  const float* mw2    = (const float*)d_in[19];
  const float* mb2    = (const float*)d_in[20];

  char* ws = (char*)d_ws;
  float* h    = (float*)(ws + 0);            // 16MB (h, later x1)
  float* z    = (float*)(ws + 16777216);     // 33.5MB (z, later ya in-place)
  float* xcp  = (float*)(ws + 50331648);     // 33.5MB (xc_pre, later h2)
  float* xs   = (float*)(ws + 83886080);     // 33.5MB
  float* dAt  = (float*)(ws + 117440512);    // 33.5MB transposed deltaA
  float* featt= (float*)(ws + 150994944);    // 33.5MB transposed feat -> scan buf
  float* Cs   = (float*)(ws + 184549376);
  float* ssq  = (float*)(ws + 184680448);
  float* wr   = (float*)(ws + 184811520);
  float* wd   = (float*)(ws + 184942592);
  unsigned int* topo32 = (unsigned int*)(ws + 185073664);   // 128KB
  int*   levs = (int*)(ws + 185335808);
  float* midg = xs;      // 67MB spans xs+dAt (both dead by then)
  float* x1   = h;
  float* h2   = xcp;

  ln128_kernel<<<MROWS / 4, 256, 0, stream>>>(x, ln1g, ln1b, h, 1e-6f);
  gemm128_kernel<1><<<dim3(4, 256), 256, 0, stream>>>(h, w_in, xcp, z, nullptr,
                                                      MROWS, 512, 128);
  convfeat_kernel<<<MROWS, 256, 0, stream>>>(xcp, conv_w, xw, dtw, dtb, alogs,
                                             xs, dAt, featt, Cs, ssq);
  gridw_kernel<<<MROWS, 256, 0, stream>>>(xs, ssq, wr, wd);
  mst_kernel<<<NB, 1024, 0, stream>>>(wr, wd, topo32, levs);
  scan_kernel<<<512, 64, 0, stream>>>(featt, dAt, topo32, levs);
  post_kernel<<<MROWS, 256, 0, stream>>>(featt, Cs, xs, dsv, hng, hnb, ong, onb, z);
  gemm_kernel<2><<<dim3(2, 512), 256, 0, stream>>>(z, w_out, x1, nullptr, nullptr, x,
                                                   MROWS, 128, 256);
  ln128_kernel<<<MROWS / 4, 256, 0, stream>>>(x1, ln2g, ln2b, h2, 1e-6f);
  gemm128_kernel<3><<<dim3(4, 256), 256, 0, stream>>>(h2, mw1, midg, nullptr, mb1,
                                                      MROWS, 512, 128);
  gemm_kernel<4><<<dim3(2, 512), 256, 0, stream>>>(midg, mw2, (float*)d_out, nullptr,
                                                   mb2, x1, MROWS, 128, 512);
}